// Round 2
// baseline (5487.879 us; speedup 1.0000x reference)
//
#include <hip/hip_runtime.h>
#include <hip/hip_bf16.h>

// Model sizes
#define N_USER 50000
#define N_REPO 100000
#define NEDGE  1000000
#define NPAIR  200000
#define D_IN   256
#define D_EMB  125
#define D_HID  96
#define D_OUT  64

// ---------------------------------------------------------------------------
// Degree histogram (float counts via atomicAdd; exact for counts < 2^24)
// ---------------------------------------------------------------------------
__global__ void deg_count(const int* __restrict__ src, const int* __restrict__ dst,
                          float* __restrict__ dsrc, float* __restrict__ ddst, int ne)
{
    int tid = blockIdx.x * blockDim.x + threadIdx.x;
    if (tid >= ne) return;
    atomicAdd(&dsrc[src[tid]], 1.0f);
    atomicAdd(&ddst[dst[tid]], 1.0f);
}

__global__ void deg_rsqrt(float* __restrict__ x, int n)
{
    int tid = blockIdx.x * blockDim.x + threadIdx.x;
    if (tid >= n) return;
    x[tid] = rsqrtf(fmaxf(x[tid], 1.0f));
}

// ---------------------------------------------------------------------------
// Fused fp32 GEMM: C = op( (A .* scaleA?) @ W + bias? + (msg .* msg_scale? + msg_bias?)? )
// BM=BN=64, BK=16, 256 threads, 4x4 microtile.
// ---------------------------------------------------------------------------
__global__ __launch_bounds__(256) void gemm_fused(
    const float* __restrict__ A, const float* __restrict__ W,
    const float* __restrict__ bias,       // [N] or null
    const float* __restrict__ scaleA,     // [M] or null (per-row pre-scale of A)
    const float* __restrict__ msg,        // [M*N] or null
    const float* __restrict__ msg_scale,  // [M] or null
    const float* __restrict__ msg_bias,   // [N] or null
    float* __restrict__ C,
    int M, int N, int K, int relu)
{
    __shared__ float As[16][65];  // +1 pad: avoid 16-way bank conflict on store
    __shared__ float Bs[16][64];
    const int tx = threadIdx.x & 15, ty = threadIdx.x >> 4;
    const int row0 = blockIdx.y * 64, col0 = blockIdx.x * 64;
    float acc[4][4] = {};

    for (int k0 = 0; k0 < K; k0 += 16) {
        #pragma unroll
        for (int l = 0; l < 4; ++l) {
            int lin = threadIdx.x + l * 256;
            int kk = lin & 15, i = lin >> 4;
            int r = row0 + i, k = k0 + kk;
            float v = 0.0f;
            if (r < M && k < K) {
                v = A[(size_t)r * K + k];
                if (scaleA) v *= scaleA[r];
            }
            As[kk][i] = v;
        }
        #pragma unroll
        for (int l = 0; l < 4; ++l) {
            int lin = threadIdx.x + l * 256;
            int j = lin & 63, kk = lin >> 6;
            int k = k0 + kk, c = col0 + j;
            Bs[kk][j] = (k < K && c < N) ? W[(size_t)k * N + c] : 0.0f;
        }
        __syncthreads();
        #pragma unroll
        for (int kk = 0; kk < 16; ++kk) {
            float a[4], b[4];
            #pragma unroll
            for (int m = 0; m < 4; ++m) a[m] = As[kk][ty + m * 16];
            #pragma unroll
            for (int n = 0; n < 4; ++n) b[n] = Bs[kk][tx + n * 16];
            #pragma unroll
            for (int m = 0; m < 4; ++m)
                #pragma unroll
                for (int n = 0; n < 4; ++n)
                    acc[m][n] += a[m] * b[n];
        }
        __syncthreads();
    }

    #pragma unroll
    for (int m = 0; m < 4; ++m) {
        int r = row0 + ty + m * 16;
        if (r >= M) continue;
        float ms = (msg && msg_scale) ? msg_scale[r] : 1.0f;
        #pragma unroll
        for (int n = 0; n < 4; ++n) {
            int c = col0 + tx + n * 16;
            if (c >= N) continue;
            float v = acc[m][n];
            if (bias) v += bias[c];
            if (msg) {
                float mv = msg[(size_t)r * N + c] * ms;
                if (msg_bias) mv += msg_bias[c];
                v += mv;
            }
            if (relu) v = fmaxf(v, 0.0f);
            C[(size_t)r * N + c] = v;
        }
    }
}

// ---------------------------------------------------------------------------
// Gather feat[src[e]] and atomic scatter-add into agg[dst[e]].
// One thread per (edge, float4-group).
// ---------------------------------------------------------------------------
__global__ void scatter_add(const float* __restrict__ feat,
                            const int* __restrict__ src, const int* __restrict__ dst,
                            float* __restrict__ agg, int ne, int d4)
{
    int tid = blockIdx.x * blockDim.x + threadIdx.x;
    int total = ne * d4;
    if (tid >= total) return;
    int e = tid / d4;
    int q = tid - e * d4;
    int s = src[e], d = dst[e];
    float4 v = ((const float4*)feat)[(size_t)s * d4 + q];
    float* out = agg + ((size_t)d * d4 + q) * 4;
    atomicAdd(out + 0, v.x);
    atomicAdd(out + 1, v.y);
    atomicAdd(out + 2, v.z);
    atomicAdd(out + 3, v.w);
}

// ---------------------------------------------------------------------------
// L2-normalize rows of [nrows x 64], in place. One wave (64 lanes) per row.
// ---------------------------------------------------------------------------
__global__ void normalize_rows64(float* __restrict__ h, int nrows)
{
    int g = (blockIdx.x * blockDim.x + threadIdx.x) >> 6;
    int lane = threadIdx.x & 63;
    if (g >= nrows) return;
    float v = h[(size_t)g * 64 + lane];
    float s = v * v;
    #pragma unroll
    for (int off = 32; off; off >>= 1) s += __shfl_xor(s, off);
    float nrm = fmaxf(sqrtf(s), 1e-12f);
    h[(size_t)g * 64 + lane] = v / nrm;
}

// ---------------------------------------------------------------------------
// Cosine score of pre-normalized vectors. One wave per pair.
// ---------------------------------------------------------------------------
__global__ void score_pairs(const float* __restrict__ nu, const float* __restrict__ nr,
                            const int* __restrict__ iu, const int* __restrict__ ir,
                            float* __restrict__ out, int np)
{
    int g = (blockIdx.x * blockDim.x + threadIdx.x) >> 6;
    int lane = threadIdx.x & 63;
    if (g >= np) return;
    float a = nu[(size_t)iu[g] * 64 + lane];
    float b = nr[(size_t)ir[g] * 64 + lane];
    float s = a * b;
    #pragma unroll
    for (int off = 32; off; off >>= 1) s += __shfl_xor(s, off);
    if (lane == 0) out[g] = s;
}

// ---------------------------------------------------------------------------
extern "C" void kernel_launch(void* const* d_in, const int* in_sizes, int n_in,
                              void* d_out, int out_size, void* d_ws, size_t ws_size,
                              hipStream_t stream)
{
    const float* user_feat = (const float*)d_in[0];
    const float* repo_feat = (const float*)d_in[1];
    const float* W_ue  = (const float*)d_in[2];   const float* b_ue  = (const float*)d_in[3];
    const float* W_re  = (const float*)d_in[4];   const float* b_re  = (const float*)d_in[5];
    const float* W_hur = (const float*)d_in[6];   const float* b_hur = (const float*)d_in[7];
    const float* W_hru = (const float*)d_in[8];   const float* b_hru = (const float*)d_in[9];
    const float* W_our = (const float*)d_in[10];  const float* b_our = (const float*)d_in[11];
    const float* W_oru = (const float*)d_in[12];  const float* b_oru = (const float*)d_in[13];
    const float* W_hcu = (const float*)d_in[14];  const float* b_hcu = (const float*)d_in[15];
    const float* W_hcr = (const float*)d_in[16];  const float* b_hcr = (const float*)d_in[17];
    const float* W_ocu = (const float*)d_in[18];  const float* b_ocu = (const float*)d_in[19];
    const float* W_ocr = (const float*)d_in[20];  const float* b_ocr = (const float*)d_in[21];
    const int* e_ur_src = (const int*)d_in[22];
    const int* e_ur_dst = (const int*)d_in[23];
    const int* e_ru_src = (const int*)d_in[24];
    const int* e_ru_dst = (const int*)d_in[25];
    const int* pos_u = (const int*)d_in[26];
    const int* pos_r = (const int*)d_in[27];
    const int* neg_u = (const int*)d_in[28];
    const int* neg_r = (const int*)d_in[29];

    float* ws = (float*)d_ws;
    // Workspace layout (floats), with late-stage reuse of A/B/C/D/E regions.
    float* A    = ws;                       // h_user   [50000 x 125]; later h_user_new [50000 x 64]
    float* B    = A + (size_t)N_USER * D_EMB;   // h_repo [100000 x 125]; later h_repo_new [100000 x 64]
    float* Cbuf = B + (size_t)N_REPO * D_EMB;   // feat buffer, max [100000 x 96]
    float* Dmsg = Cbuf + (size_t)N_REPO * D_HID; // agg->user, max [50000 x 96]
    float* Emsg = Dmsg + (size_t)N_USER * D_HID; // agg->repo, max [100000 x 96]
    float* F    = Emsg + (size_t)N_REPO * D_HID; // out_user [50000 x 96]
    float* G    = F + (size_t)N_USER * D_HID;    // out_repo [100000 x 96]
    float* RS   = G + (size_t)N_REPO * D_HID;    // 4 rsqrt-degree arrays, 300000 floats
    float* rs_ur_src = RS;                    // user out-deg in ur graph [50000]
    float* rs_ur_dst = RS + N_USER;           // repo in-deg  in ur graph [100000]
    float* rs_ru_src = rs_ur_dst + N_REPO;    // repo out-deg in ru graph [100000]
    float* rs_ru_dst = rs_ru_src + N_REPO;    // user in-deg  in ru graph [50000]

    const int BLK = 256;
    auto grid1 = [&](long n) { return dim3((unsigned)((n + BLK - 1) / BLK)); };

    // ---- degrees ----
    hipMemsetAsync(RS, 0, 300000 * sizeof(float), stream);
    deg_count<<<grid1(NEDGE), BLK, 0, stream>>>(e_ur_src, e_ur_dst, rs_ur_src, rs_ur_dst, NEDGE);
    deg_count<<<grid1(NEDGE), BLK, 0, stream>>>(e_ru_src, e_ru_dst, rs_ru_src, rs_ru_dst, NEDGE);
    deg_rsqrt<<<grid1(300000), BLK, 0, stream>>>(RS, 300000);

    auto gemm = [&](const float* Ap, const float* Wp, const float* biasp,
                    const float* scalep, const float* msgp, const float* msscale,
                    const float* msbias, float* Cp, int M, int N, int K, int relu) {
        dim3 g((N + 63) / 64, (M + 63) / 64);
        gemm_fused<<<g, 256, 0, stream>>>(Ap, Wp, biasp, scalep, msgp, msscale, msbias,
                                          Cp, M, N, K, relu);
    };

    // ---- embeddings ----
    gemm(user_feat, W_ue, b_ue, nullptr, nullptr, nullptr, nullptr, A, N_USER, D_EMB, D_IN, 0);
    gemm(repo_feat, W_re, b_re, nullptr, nullptr, nullptr, nullptr, B, N_REPO, D_EMB, D_IN, 0);

    // ---- hidden conv: ru (repo -> user) ----
    gemm(B, W_hru, nullptr, rs_ru_src, nullptr, nullptr, nullptr, Cbuf, N_REPO, D_HID, D_EMB, 0);
    hipMemsetAsync(Dmsg, 0, (size_t)N_USER * D_HID * sizeof(float), stream);
    scatter_add<<<grid1((long)NEDGE * (D_HID / 4)), BLK, 0, stream>>>(
        Cbuf, e_ru_src, e_ru_dst, Dmsg, NEDGE, D_HID / 4);

    // ---- hidden conv: ur (user -> repo) ----
    gemm(A, W_hur, nullptr, rs_ur_src, nullptr, nullptr, nullptr, Cbuf, N_USER, D_HID, D_EMB, 0);
    hipMemsetAsync(Emsg, 0, (size_t)N_REPO * D_HID * sizeof(float), stream);
    scatter_add<<<grid1((long)NEDGE * (D_HID / 4)), BLK, 0, stream>>>(
        Cbuf, e_ur_src, e_ur_dst, Emsg, NEDGE, D_HID / 4);

    // ---- residual + relu ----
    gemm(A, W_hcu, b_hcu, nullptr, Dmsg, rs_ru_dst, b_hru, F, N_USER, D_HID, D_EMB, 1);
    gemm(B, W_hcr, b_hcr, nullptr, Emsg, rs_ur_dst, b_hur, G, N_REPO, D_HID, D_EMB, 1);

    // ---- output conv: ru ----
    gemm(G, W_oru, nullptr, rs_ru_src, nullptr, nullptr, nullptr, Cbuf, N_REPO, D_OUT, D_HID, 0);
    hipMemsetAsync(Dmsg, 0, (size_t)N_USER * D_OUT * sizeof(float), stream);
    scatter_add<<<grid1((long)NEDGE * (D_OUT / 4)), BLK, 0, stream>>>(
        Cbuf, e_ru_src, e_ru_dst, Dmsg, NEDGE, D_OUT / 4);

    // ---- output conv: ur ----
    gemm(F, W_our, nullptr, rs_ur_src, nullptr, nullptr, nullptr, Cbuf, N_USER, D_OUT, D_HID, 0);
    hipMemsetAsync(Emsg, 0, (size_t)N_REPO * D_OUT * sizeof(float), stream);
    scatter_add<<<grid1((long)NEDGE * (D_OUT / 4)), BLK, 0, stream>>>(
        Cbuf, e_ur_src, e_ur_dst, Emsg, NEDGE, D_OUT / 4);

    // ---- final nodes (reuse A/B regions) ----
    gemm(F, W_ocu, b_ocu, nullptr, Dmsg, rs_ru_dst, b_oru, A, N_USER, D_OUT, D_HID, 1);
    gemm(G, W_ocr, b_ocr, nullptr, Emsg, rs_ur_dst, b_our, B, N_REPO, D_OUT, D_HID, 1);

    normalize_rows64<<<grid1((long)N_USER * 64), BLK, 0, stream>>>(A, N_USER);
    normalize_rows64<<<grid1((long)N_REPO * 64), BLK, 0, stream>>>(B, N_REPO);

    // ---- scores ----
    float* out = (float*)d_out;
    score_pairs<<<grid1((long)NPAIR * 64), BLK, 0, stream>>>(A, B, pos_u, pos_r, out, NPAIR);
    score_pairs<<<grid1((long)NPAIR * 64), BLK, 0, stream>>>(A, B, neg_u, neg_r, out + NPAIR, NPAIR);
}

// Round 3
// 1680.088 us; speedup vs baseline: 3.2664x; 3.2664x over previous
//
#include <hip/hip_runtime.h>
#include <hip/hip_bf16.h>

// Model sizes
#define N_USER 50000
#define N_REPO 100000
#define NEDGE  1000000
#define NPAIR  200000
#define D_IN   256
#define D_EMB  125
#define D_HID  96
#define D_OUT  64

// ---------------------------------------------------------------------------
// Int histogram of two index arrays (degree counts).
// ---------------------------------------------------------------------------
__global__ void hist2(const int* __restrict__ src, const int* __restrict__ dst,
                      int* __restrict__ cs, int* __restrict__ cd, int ne)
{
    int e = blockIdx.x * blockDim.x + threadIdx.x;
    if (e >= ne) return;
    atomicAdd(&cs[src[e]], 1);
    atomicAdd(&cd[dst[e]], 1);
}

__global__ void rsqrt_int(const int* __restrict__ cnt, float* __restrict__ rs, int n)
{
    int i = blockIdx.x * blockDim.x + threadIdx.x;
    if (i >= n) return;
    rs[i] = rsqrtf((float)max(cnt[i], 1));
}

// ---------------------------------------------------------------------------
// Two-level exclusive scan (for CSR offsets).
// ---------------------------------------------------------------------------
__global__ void scan_block(const int* __restrict__ cnt, int* __restrict__ off,
                           int* __restrict__ bsums, int n)
{
    __shared__ int s[256];
    int t = threadIdx.x, i = blockIdx.x * 256 + t;
    int v = (i < n) ? cnt[i] : 0;
    s[t] = v;
    __syncthreads();
    for (int d = 1; d < 256; d <<= 1) {
        int u = (t >= d) ? s[t - d] : 0;
        __syncthreads();
        s[t] += u;
        __syncthreads();
    }
    if (i < n) off[i] = s[t] - v;  // exclusive within block
    if (t == 255) bsums[blockIdx.x] = s[255];
}

__global__ void scan_sums(int* __restrict__ b, int nb)  // single block, nb <= 512
{
    __shared__ int s[512];
    int t = threadIdx.x;
    s[t] = (t < nb) ? b[t] : 0;
    __syncthreads();
    for (int d = 1; d < 512; d <<= 1) {
        int v = (t >= d) ? s[t - d] : 0;
        __syncthreads();
        s[t] += v;
        __syncthreads();
    }
    if (t < nb) b[t] = s[t];  // inclusive
}

__global__ void scan_fix(int* __restrict__ off, const int* __restrict__ bsums,
                         int n, int total)
{
    int i = blockIdx.x * 256 + threadIdx.x;
    if (i > n) return;
    if (i == n) { off[n] = total; return; }
    int blk = i >> 8;
    if (blk > 0) off[i] += bsums[blk - 1];
}

// ---------------------------------------------------------------------------
// CSR fill: cur[] must be a copy of off[]; csr[pos] = src of edges grouped by dst.
// ---------------------------------------------------------------------------
__global__ void fill_csr(const int* __restrict__ src, const int* __restrict__ dst,
                         int* __restrict__ cur, int* __restrict__ csr, int ne)
{
    int e = blockIdx.x * blockDim.x + threadIdx.x;
    if (e >= ne) return;
    int p = atomicAdd(&cur[dst[e]], 1);
    csr[p] = src[e];
}

// ---------------------------------------------------------------------------
// Pull-mode segment sum: agg[node] = sum over incoming edges of feat[csr_src].
// Thread = (node, float4 column). nb nodes per 256-thread block.
// ---------------------------------------------------------------------------
__global__ void segment_sum(const float* __restrict__ feat, const int* __restrict__ csr,
                            const int* __restrict__ off, float* __restrict__ agg,
                            int n_dst, int d4, int nb)
{
    int local = threadIdx.x;
    int ni = local / d4;
    int c4 = local - ni * d4;
    if (ni >= nb) return;
    int node = blockIdx.x * nb + ni;
    if (node >= n_dst) return;
    int j0 = off[node], j1 = off[node + 1];
    float4 acc = {0.f, 0.f, 0.f, 0.f};
    for (int j = j0; j < j1; ++j) {
        int s = csr[j];
        float4 v = ((const float4*)feat)[(size_t)s * d4 + c4];
        acc.x += v.x; acc.y += v.y; acc.z += v.z; acc.w += v.w;
    }
    ((float4*)agg)[(size_t)node * d4 + c4] = acc;
}

// ---------------------------------------------------------------------------
// Fused fp32 GEMM: C = op( (A .* scaleA?) @ W + bias? + (msg .* msg_scale? + msg_bias?)? )
// BM=BN=64, BK=16, 256 threads, 4x4 microtile.
// ---------------------------------------------------------------------------
__global__ __launch_bounds__(256) void gemm_fused(
    const float* __restrict__ A, const float* __restrict__ W,
    const float* __restrict__ bias,       // [N] or null
    const float* __restrict__ scaleA,     // [M] or null (per-row pre-scale of A)
    const float* __restrict__ msg,        // [M*N] or null
    const float* __restrict__ msg_scale,  // [M] or null
    const float* __restrict__ msg_bias,   // [N] or null
    float* __restrict__ C,
    int M, int N, int K, int relu)
{
    __shared__ float As[16][65];
    __shared__ float Bs[16][64];
    const int tx = threadIdx.x & 15, ty = threadIdx.x >> 4;
    const int row0 = blockIdx.y * 64, col0 = blockIdx.x * 64;
    float acc[4][4] = {};

    for (int k0 = 0; k0 < K; k0 += 16) {
        #pragma unroll
        for (int l = 0; l < 4; ++l) {
            int lin = threadIdx.x + l * 256;
            int kk = lin & 15, i = lin >> 4;
            int r = row0 + i, k = k0 + kk;
            float v = 0.0f;
            if (r < M && k < K) {
                v = A[(size_t)r * K + k];
                if (scaleA) v *= scaleA[r];
            }
            As[kk][i] = v;
        }
        #pragma unroll
        for (int l = 0; l < 4; ++l) {
            int lin = threadIdx.x + l * 256;
            int j = lin & 63, kk = lin >> 6;
            int k = k0 + kk, c = col0 + j;
            Bs[kk][j] = (k < K && c < N) ? W[(size_t)k * N + c] : 0.0f;
        }
        __syncthreads();
        #pragma unroll
        for (int kk = 0; kk < 16; ++kk) {
            float a[4], b[4];
            #pragma unroll
            for (int m = 0; m < 4; ++m) a[m] = As[kk][ty + m * 16];
            #pragma unroll
            for (int n = 0; n < 4; ++n) b[n] = Bs[kk][tx + n * 16];
            #pragma unroll
            for (int m = 0; m < 4; ++m)
                #pragma unroll
                for (int n = 0; n < 4; ++n)
                    acc[m][n] += a[m] * b[n];
        }
        __syncthreads();
    }

    #pragma unroll
    for (int m = 0; m < 4; ++m) {
        int r = row0 + ty + m * 16;
        if (r >= M) continue;
        float ms = (msg && msg_scale) ? msg_scale[r] : 1.0f;
        #pragma unroll
        for (int n = 0; n < 4; ++n) {
            int c = col0 + tx + n * 16;
            if (c >= N) continue;
            float v = acc[m][n];
            if (bias) v += bias[c];
            if (msg) {
                float mv = msg[(size_t)r * N + c] * ms;
                if (msg_bias) mv += msg_bias[c];
                v += mv;
            }
            if (relu) v = fmaxf(v, 0.0f);
            C[(size_t)r * N + c] = v;
        }
    }
}

// ---------------------------------------------------------------------------
// L2-normalize rows of [nrows x 64], in place. One wave per row.
// ---------------------------------------------------------------------------
__global__ void normalize_rows64(float* __restrict__ h, int nrows)
{
    int g = (blockIdx.x * blockDim.x + threadIdx.x) >> 6;
    int lane = threadIdx.x & 63;
    if (g >= nrows) return;
    float v = h[(size_t)g * 64 + lane];
    float s = v * v;
    #pragma unroll
    for (int off = 32; off; off >>= 1) s += __shfl_xor(s, off);
    float nrm = fmaxf(sqrtf(s), 1e-12f);
    h[(size_t)g * 64 + lane] = v / nrm;
}

// ---------------------------------------------------------------------------
// Cosine score of pre-normalized vectors. One wave per pair.
// ---------------------------------------------------------------------------
__global__ void score_pairs(const float* __restrict__ nu, const float* __restrict__ nr,
                            const int* __restrict__ iu, const int* __restrict__ ir,
                            float* __restrict__ out, int np)
{
    int g = (blockIdx.x * blockDim.x + threadIdx.x) >> 6;
    int lane = threadIdx.x & 63;
    if (g >= np) return;
    float a = nu[(size_t)iu[g] * 64 + lane];
    float b = nr[(size_t)ir[g] * 64 + lane];
    float s = a * b;
    #pragma unroll
    for (int off = 32; off; off >>= 1) s += __shfl_xor(s, off);
    if (lane == 0) out[g] = s;
}

// ---------------------------------------------------------------------------
extern "C" void kernel_launch(void* const* d_in, const int* in_sizes, int n_in,
                              void* d_out, int out_size, void* d_ws, size_t ws_size,
                              hipStream_t stream)
{
    const float* user_feat = (const float*)d_in[0];
    const float* repo_feat = (const float*)d_in[1];
    const float* W_ue  = (const float*)d_in[2];   const float* b_ue  = (const float*)d_in[3];
    const float* W_re  = (const float*)d_in[4];   const float* b_re  = (const float*)d_in[5];
    const float* W_hur = (const float*)d_in[6];   const float* b_hur = (const float*)d_in[7];
    const float* W_hru = (const float*)d_in[8];   const float* b_hru = (const float*)d_in[9];
    const float* W_our = (const float*)d_in[10];  const float* b_our = (const float*)d_in[11];
    const float* W_oru = (const float*)d_in[12];  const float* b_oru = (const float*)d_in[13];
    const float* W_hcu = (const float*)d_in[14];  const float* b_hcu = (const float*)d_in[15];
    const float* W_hcr = (const float*)d_in[16];  const float* b_hcr = (const float*)d_in[17];
    const float* W_ocu = (const float*)d_in[18];  const float* b_ocu = (const float*)d_in[19];
    const float* W_ocr = (const float*)d_in[20];  const float* b_ocr = (const float*)d_in[21];
    const int* e_ur_src = (const int*)d_in[22];
    const int* e_ur_dst = (const int*)d_in[23];
    const int* e_ru_src = (const int*)d_in[24];
    const int* e_ru_dst = (const int*)d_in[25];
    const int* pos_u = (const int*)d_in[26];
    const int* pos_r = (const int*)d_in[27];
    const int* neg_u = (const int*)d_in[28];
    const int* neg_r = (const int*)d_in[29];

    float* ws = (float*)d_ws;
    // ---- float workspace ----
    float* A    = ws;                            // h_user [50000x125]; later h_user_new [50000x64]
    float* B    = A + (size_t)N_USER * D_EMB;    // h_repo [100000x125]; later h_repo_new [100000x64]
    float* Cbuf = B + (size_t)N_REPO * D_EMB;    // feat buffer, max [100000x96]
    float* Dmsg = Cbuf + (size_t)N_REPO * D_HID; // agg -> user, max [50000x96]
    float* Emsg = Dmsg + (size_t)N_USER * D_HID; // agg -> repo, max [100000x96]
    float* F    = Emsg + (size_t)N_REPO * D_HID; // out_user [50000x96]
    float* G    = F + (size_t)N_USER * D_HID;    // out_repo [100000x96]
    float* RS   = G + (size_t)N_REPO * D_HID;    // 4 rsqrt-degree arrays, 300000 floats
    float* rs_ur_src = RS;                       // user out-deg (ur) [50000]
    float* rs_ur_dst = RS + N_USER;              // repo in-deg  (ur) [100000]
    float* rs_ru_src = rs_ur_dst + N_REPO;       // repo out-deg (ru) [100000]
    float* rs_ru_dst = rs_ru_src + N_REPO;       // user in-deg  (ru) [50000]
    // ---- int workspace (CSR) ----
    int* CNT = (int*)(RS + 300000);              // degree counts, same layout as RS [300000]
    int* cnt_ur_src = CNT;
    int* cnt_ur_dst = CNT + N_USER;
    int* cnt_ru_src = cnt_ur_dst + N_REPO;
    int* cnt_ru_dst = cnt_ru_src + N_REPO;
    int* off_ur  = CNT + 300000;                 // [N_REPO+1]
    int* off_ru  = off_ur + (N_REPO + 1);        // [N_USER+1]
    int* cur_ur  = off_ru + (N_USER + 1);        // [N_REPO]
    int* cur_ru  = cur_ur + N_REPO;              // [N_USER]
    int* bs_ur   = cur_ru + N_USER;              // [512]
    int* bs_ru   = bs_ur + 512;                  // [512]
    int* csr_ur  = bs_ru + 512;                  // [NEDGE] user ids grouped by repo dst
    int* csr_ru  = csr_ur + NEDGE;               // [NEDGE] repo ids grouped by user dst

    const int BLK = 256;
    auto grid1 = [&](long n) { return dim3((unsigned)((n + BLK - 1) / BLK)); };

    // ---- degrees + CSR build ----
    hipMemsetAsync(CNT, 0, 300000 * sizeof(int), stream);
    hist2<<<grid1(NEDGE), BLK, 0, stream>>>(e_ur_src, e_ur_dst, cnt_ur_src, cnt_ur_dst, NEDGE);
    hist2<<<grid1(NEDGE), BLK, 0, stream>>>(e_ru_src, e_ru_dst, cnt_ru_src, cnt_ru_dst, NEDGE);
    rsqrt_int<<<grid1(300000), BLK, 0, stream>>>(CNT, RS, 300000);

    // scan ur (n = N_REPO = 100000, 391 blocks)
    {
        int nb = (N_REPO + 255) / 256;
        scan_block<<<nb, 256, 0, stream>>>(cnt_ur_dst, off_ur, bs_ur, N_REPO);
        scan_sums<<<1, 512, 0, stream>>>(bs_ur, nb);
        scan_fix<<<grid1(N_REPO + 1), 256, 0, stream>>>(off_ur, bs_ur, N_REPO, NEDGE);
    }
    // scan ru (n = N_USER = 50000, 196 blocks)
    {
        int nb = (N_USER + 255) / 256;
        scan_block<<<nb, 256, 0, stream>>>(cnt_ru_dst, off_ru, bs_ru, N_USER);
        scan_sums<<<1, 512, 0, stream>>>(bs_ru, nb);
        scan_fix<<<grid1(N_USER + 1), 256, 0, stream>>>(off_ru, bs_ru, N_USER, NEDGE);
    }
    hipMemcpyAsync(cur_ur, off_ur, N_REPO * sizeof(int), hipMemcpyDeviceToDevice, stream);
    hipMemcpyAsync(cur_ru, off_ru, N_USER * sizeof(int), hipMemcpyDeviceToDevice, stream);
    fill_csr<<<grid1(NEDGE), BLK, 0, stream>>>(e_ur_src, e_ur_dst, cur_ur, csr_ur, NEDGE);
    fill_csr<<<grid1(NEDGE), BLK, 0, stream>>>(e_ru_src, e_ru_dst, cur_ru, csr_ru, NEDGE);

    auto gemm = [&](const float* Ap, const float* Wp, const float* biasp,
                    const float* scalep, const float* msgp, const float* msscale,
                    const float* msbias, float* Cp, int M, int N, int K, int relu) {
        dim3 g((N + 63) / 64, (M + 63) / 64);
        gemm_fused<<<g, 256, 0, stream>>>(Ap, Wp, biasp, scalep, msgp, msscale, msbias,
                                          Cp, M, N, K, relu);
    };
    auto segsum = [&](const float* feat, const int* csr, const int* off, float* agg,
                      int n_dst, int D) {
        int d4 = D / 4;
        int nb = 256 / d4;  // nodes per block
        segment_sum<<<(n_dst + nb - 1) / nb, 256, 0, stream>>>(feat, csr, off, agg,
                                                               n_dst, d4, nb);
    };

    // ---- embeddings ----
    gemm(user_feat, W_ue, b_ue, nullptr, nullptr, nullptr, nullptr, A, N_USER, D_EMB, D_IN, 0);
    gemm(repo_feat, W_re, b_re, nullptr, nullptr, nullptr, nullptr, B, N_REPO, D_EMB, D_IN, 0);

    // ---- hidden conv: ru (repo -> user) ----
    gemm(B, W_hru, nullptr, rs_ru_src, nullptr, nullptr, nullptr, Cbuf, N_REPO, D_HID, D_EMB, 0);
    segsum(Cbuf, csr_ru, off_ru, Dmsg, N_USER, D_HID);

    // ---- hidden conv: ur (user -> repo) ----
    gemm(A, W_hur, nullptr, rs_ur_src, nullptr, nullptr, nullptr, Cbuf, N_USER, D_HID, D_EMB, 0);
    segsum(Cbuf, csr_ur, off_ur, Emsg, N_REPO, D_HID);

    // ---- residual + relu ----
    gemm(A, W_hcu, b_hcu, nullptr, Dmsg, rs_ru_dst, b_hru, F, N_USER, D_HID, D_EMB, 1);
    gemm(B, W_hcr, b_hcr, nullptr, Emsg, rs_ur_dst, b_hur, G, N_REPO, D_HID, D_EMB, 1);

    // ---- output conv: ru ----
    gemm(G, W_oru, nullptr, rs_ru_src, nullptr, nullptr, nullptr, Cbuf, N_REPO, D_OUT, D_HID, 0);
    segsum(Cbuf, csr_ru, off_ru, Dmsg, N_USER, D_OUT);

    // ---- output conv: ur ----
    gemm(F, W_our, nullptr, rs_ur_src, nullptr, nullptr, nullptr, Cbuf, N_USER, D_OUT, D_HID, 0);
    segsum(Cbuf, csr_ur, off_ur, Emsg, N_REPO, D_OUT);

    // ---- final nodes (reuse A/B regions) ----
    gemm(F, W_ocu, b_ocu, nullptr, Dmsg, rs_ru_dst, b_oru, A, N_USER, D_OUT, D_HID, 1);
    gemm(G, W_ocr, b_ocr, nullptr, Emsg, rs_ur_dst, b_our, B, N_REPO, D_OUT, D_HID, 1);

    normalize_rows64<<<grid1((long)N_USER * 64), BLK, 0, stream>>>(A, N_USER);
    normalize_rows64<<<grid1((long)N_REPO * 64), BLK, 0, stream>>>(B, N_REPO);

    // ---- scores ----
    float* out = (float*)d_out;
    score_pairs<<<grid1((long)NPAIR * 64), BLK, 0, stream>>>(A, B, pos_u, pos_r, out, NPAIR);
    score_pairs<<<grid1((long)NPAIR * 64), BLK, 0, stream>>>(A, B, neg_u, neg_r, out + NPAIR, NPAIR);
}

// Round 4
// 1102.510 us; speedup vs baseline: 4.9776x; 1.5239x over previous
//
#include <hip/hip_runtime.h>
#include <hip/hip_bf16.h>

// Model sizes
#define N_USER 50000
#define N_REPO 100000
#define NEDGE  1000000
#define NPAIR  200000
#define D_IN   256
#define D_EMB  125
#define D_EMB_P 128
#define D_HID  96
#define D_OUT  64

typedef short bf16x8 __attribute__((ext_vector_type(8)));
typedef float f32x4 __attribute__((ext_vector_type(4)));
typedef unsigned short ushort8 __attribute__((ext_vector_type(8)));

__device__ __forceinline__ unsigned short f2bf(float x) {
    union { float f; unsigned u; } c; c.f = x;
    unsigned r = c.u + 0x7fffu + ((c.u >> 16) & 1u);
    return (unsigned short)(r >> 16);
}
__device__ __forceinline__ float bf2f(unsigned short b) {
    union { unsigned u; float f; } c; c.u = ((unsigned)b) << 16;
    return c.f;
}

// ---------------------------------------------------------------------------
// Degree histograms / CSR build
// ---------------------------------------------------------------------------
__global__ void hist2(const int* __restrict__ src, const int* __restrict__ dst,
                      int* __restrict__ cs, int* __restrict__ cd, int ne)
{
    int e = blockIdx.x * blockDim.x + threadIdx.x;
    if (e >= ne) return;
    atomicAdd(&cs[src[e]], 1);
    atomicAdd(&cd[dst[e]], 1);
}

__global__ void rsqrt_int(const int* __restrict__ cnt, float* __restrict__ rs, int n)
{
    int i = blockIdx.x * blockDim.x + threadIdx.x;
    if (i >= n) return;
    rs[i] = rsqrtf((float)max(cnt[i], 1));
}

__global__ void scan_block(const int* __restrict__ cnt, int* __restrict__ off,
                           int* __restrict__ bsums, int n)
{
    __shared__ int s[256];
    int t = threadIdx.x, i = blockIdx.x * 256 + t;
    int v = (i < n) ? cnt[i] : 0;
    s[t] = v;
    __syncthreads();
    for (int d = 1; d < 256; d <<= 1) {
        int u = (t >= d) ? s[t - d] : 0;
        __syncthreads();
        s[t] += u;
        __syncthreads();
    }
    if (i < n) off[i] = s[t] - v;
    if (t == 255) bsums[blockIdx.x] = s[255];
}

__global__ void scan_sums(int* __restrict__ b, int nb)
{
    __shared__ int s[512];
    int t = threadIdx.x;
    s[t] = (t < nb) ? b[t] : 0;
    __syncthreads();
    for (int d = 1; d < 512; d <<= 1) {
        int v = (t >= d) ? s[t - d] : 0;
        __syncthreads();
        s[t] += v;
        __syncthreads();
    }
    if (t < nb) b[t] = s[t];
}

__global__ void scan_fix(int* __restrict__ off, const int* __restrict__ bsums,
                         int n, int total)
{
    int i = blockIdx.x * 256 + threadIdx.x;
    if (i > n) return;
    if (i == n) { off[n] = total; return; }
    int blk = i >> 8;
    if (blk > 0) off[i] += bsums[blk - 1];
}

__global__ void fill_csr(const int* __restrict__ src, const int* __restrict__ dst,
                         int* __restrict__ cur, int* __restrict__ csr, int ne)
{
    int e = blockIdx.x * blockDim.x + threadIdx.x;
    if (e >= ne) return;
    int p = atomicAdd(&cur[dst[e]], 1);
    csr[p] = src[e];
}

// ---------------------------------------------------------------------------
// Weight convert: WT[n][k] = bf16(W[k][n]), zero-padded to [Np][Kp]
// ---------------------------------------------------------------------------
__global__ void wconv(const float* __restrict__ W, unsigned short* __restrict__ WT,
                      int K, int N, int Kp, int Np)
{
    int idx = blockIdx.x * 256 + threadIdx.x;
    if (idx >= Np * Kp) return;
    int n = idx / Kp, k = idx - n * Kp;
    float v = (n < N && k < K) ? W[(size_t)k * N + n] : 0.0f;
    WT[idx] = f2bf(v);
}

// ---------------------------------------------------------------------------
// bf16 MFMA GEMM, BM=128, BN=NP (<=128), BK=32, 4 waves (2x2), fused epilogue.
//   C = op( (A .* scaleA?) @ W + bias? + (msg .* msg_scale? + msg_bias?)? )
// A: fp32 [M][K] (ABF=false) or bf16 [M][K] (ABF=true).  WT: bf16 [NP][K].
// Outputs: Cf fp32 [M][Nreal] (opt), Cb bf16 [M][NP] zero-padded (opt).
// LDS row stride 40 shorts -> (5r+q)%8 slot pattern, conflict-free b128 reads.
// ---------------------------------------------------------------------------
template<int NP, bool ABF>
__global__ __launch_bounds__(256) void gemm_mfma(
    const float* __restrict__ Af, const unsigned short* __restrict__ Ab,
    const unsigned short* __restrict__ WT,
    const float* __restrict__ bias, const float* __restrict__ scaleA,
    const float* __restrict__ msg, const float* __restrict__ msg_scale,
    const float* __restrict__ msg_bias,
    float* __restrict__ Cf, unsigned short* __restrict__ Cb,
    int M, int Nreal, int K, int relu)
{
    constexpr int NF = NP / 32;      // n-frags per wave (wave covers NP/2 cols)
    __shared__ unsigned short As[128 * 40];
    __shared__ unsigned short Bs[NP * 40];
    const int t = threadIdx.x;
    const int row0 = blockIdx.x * 128;
    const int w = t >> 6, l = t & 63;
    const int wr = w >> 1, wc = w & 1;
    const int lr = l & 15, q = l >> 4;

    f32x4 acc[4][NF];
    #pragma unroll
    for (int m = 0; m < 4; ++m)
        #pragma unroll
        for (int n = 0; n < NF; ++n)
            acc[m][n] = (f32x4){0.f, 0.f, 0.f, 0.f};

    const int ar = t >> 1;            // A staging: row per thread-pair
    const int ah = t & 1;             // which 16-element half of the 32-wide k strip
    const int grow = row0 + ar;

    for (int k0 = 0; k0 < K; k0 += 32) {
        // ---- stage A (128 x 32 bf16) ----
        {
            ushort8 o0, o1;
            if (grow < M) {
                if (ABF) {
                    ushort8 v0 = *(const ushort8*)(Ab + (size_t)grow * K + k0 + ah * 16);
                    ushort8 v1 = *(const ushort8*)(Ab + (size_t)grow * K + k0 + ah * 16 + 8);
                    if (scaleA) {
                        float s = scaleA[grow];
                        #pragma unroll
                        for (int i = 0; i < 8; ++i) {
                            o0[i] = f2bf(bf2f(v0[i]) * s);
                            o1[i] = f2bf(bf2f(v1[i]) * s);
                        }
                    } else { o0 = v0; o1 = v1; }
                } else {
                    float s = scaleA ? scaleA[grow] : 1.0f;
                    const float* ap = Af + (size_t)grow * K + k0 + ah * 16;
                    #pragma unroll
                    for (int j = 0; j < 2; ++j) {
                        float4 u = *(const float4*)(ap + j * 4);
                        o0[j * 4 + 0] = f2bf(u.x * s); o0[j * 4 + 1] = f2bf(u.y * s);
                        o0[j * 4 + 2] = f2bf(u.z * s); o0[j * 4 + 3] = f2bf(u.w * s);
                    }
                    #pragma unroll
                    for (int j = 0; j < 2; ++j) {
                        float4 u = *(const float4*)(ap + 8 + j * 4);
                        o1[j * 4 + 0] = f2bf(u.x * s); o1[j * 4 + 1] = f2bf(u.y * s);
                        o1[j * 4 + 2] = f2bf(u.z * s); o1[j * 4 + 3] = f2bf(u.w * s);
                    }
                }
            } else {
                #pragma unroll
                for (int i = 0; i < 8; ++i) { o0[i] = 0; o1[i] = 0; }
            }
            *(ushort8*)(As + ar * 40 + ah * 16) = o0;
            *(ushort8*)(As + ar * 40 + ah * 16 + 8) = o1;
        }
        // ---- stage B (NP x 32 bf16) from WT ----
        #pragma unroll
        for (int ch = 0; ch < NP * 4 / 256; ++ch) {
            int cid = t + ch * 256;
            int c = cid >> 2, kq = cid & 3;
            *(ushort8*)(Bs + c * 40 + kq * 8) =
                *(const ushort8*)(WT + (size_t)c * K + k0 + kq * 8);
        }
        if (NP * 4 % 256) {  // NP=96: 384 chunks, second pass partial
            int cid = t + (NP * 4 / 256) * 256;
            if (cid < NP * 4) {
                int c = cid >> 2, kq = cid & 3;
                *(ushort8*)(Bs + c * 40 + kq * 8) =
                    *(const ushort8*)(WT + (size_t)c * K + k0 + kq * 8);
            }
        }
        __syncthreads();
        // ---- compute ----
        bf16x8 a[4], b[NF];
        #pragma unroll
        for (int m = 0; m < 4; ++m)
            a[m] = *(const bf16x8*)(As + (wr * 64 + m * 16 + lr) * 40 + q * 8);
        #pragma unroll
        for (int n = 0; n < NF; ++n)
            b[n] = *(const bf16x8*)(Bs + (wc * (NP / 2) + n * 16 + lr) * 40 + q * 8);
        #pragma unroll
        for (int m = 0; m < 4; ++m)
            #pragma unroll
            for (int n = 0; n < NF; ++n)
                acc[m][n] = __builtin_amdgcn_mfma_f32_16x16x32_bf16(a[m], b[n], acc[m][n], 0, 0, 0);
        __syncthreads();
    }

    // ---- epilogue ----
    #pragma unroll
    for (int m = 0; m < 4; ++m) {
        #pragma unroll
        for (int j = 0; j < 4; ++j) {
            int r = row0 + wr * 64 + m * 16 + q * 4 + j;
            if (r >= M) continue;
            float ms = (msg && msg_scale) ? msg_scale[r] : 1.0f;
            #pragma unroll
            for (int n = 0; n < NF; ++n) {
                int c = wc * (NP / 2) + n * 16 + lr;
                float v = acc[m][n][j];
                if (c < Nreal) {
                    if (bias) v += bias[c];
                    if (msg) {
                        float mv = msg[(size_t)r * Nreal + c] * ms;
                        if (msg_bias) mv += msg_bias[c];
                        v += mv;
                    }
                    if (relu) v = fmaxf(v, 0.0f);
                    if (Cf) Cf[(size_t)r * Nreal + c] = v;
                } else {
                    v = 0.0f;
                }
                if (Cb) Cb[(size_t)r * NP + c] = f2bf(v);
            }
        }
    }
}

// ---------------------------------------------------------------------------
// Pull segment-sum over bf16 features, fp32 accumulate/write.
// Thread = (node, 8-col chunk). d8 = D/8 chunks per node, nb nodes per block.
// ---------------------------------------------------------------------------
__global__ void segment_sum_bf16(const unsigned short* __restrict__ feat,
                                 const int* __restrict__ csr, const int* __restrict__ off,
                                 float* __restrict__ agg, int n_dst, int d8, int nb)
{
    int ni = threadIdx.x / d8;
    int c8 = threadIdx.x - ni * d8;
    if (ni >= nb) return;
    int node = blockIdx.x * nb + ni;
    if (node >= n_dst) return;
    int D = d8 * 8;
    int j0 = off[node], j1 = off[node + 1];
    float acc[8] = {};
    for (int j = j0; j < j1; ++j) {
        int s = csr[j];
        ushort8 v = *(const ushort8*)(feat + (size_t)s * D + c8 * 8);
        #pragma unroll
        for (int i = 0; i < 8; ++i) acc[i] += bf2f(v[i]);
    }
    float4* o = (float4*)(agg + (size_t)node * D + c8 * 8);
    o[0] = make_float4(acc[0], acc[1], acc[2], acc[3]);
    o[1] = make_float4(acc[4], acc[5], acc[6], acc[7]);
}

// ---------------------------------------------------------------------------
// L2-normalize rows of [nrows x 64] fp32 in place; one wave per row.
// ---------------------------------------------------------------------------
__global__ void normalize_rows64(float* __restrict__ h, int nrows)
{
    int g = (blockIdx.x * blockDim.x + threadIdx.x) >> 6;
    int lane = threadIdx.x & 63;
    if (g >= nrows) return;
    float v = h[(size_t)g * 64 + lane];
    float s = v * v;
    #pragma unroll
    for (int off = 32; off; off >>= 1) s += __shfl_xor(s, off);
    float nrm = fmaxf(sqrtf(s), 1e-12f);
    h[(size_t)g * 64 + lane] = v / nrm;
}

__global__ void score_pairs(const float* __restrict__ nu, const float* __restrict__ nr,
                            const int* __restrict__ iu, const int* __restrict__ ir,
                            float* __restrict__ out, int np)
{
    int g = (blockIdx.x * blockDim.x + threadIdx.x) >> 6;
    int lane = threadIdx.x & 63;
    if (g >= np) return;
    float a = nu[(size_t)iu[g] * 64 + lane];
    float b = nr[(size_t)ir[g] * 64 + lane];
    float s = a * b;
    #pragma unroll
    for (int off = 32; off; off >>= 1) s += __shfl_xor(s, off);
    if (lane == 0) out[g] = s;
}

// ---------------------------------------------------------------------------
extern "C" void kernel_launch(void* const* d_in, const int* in_sizes, int n_in,
                              void* d_out, int out_size, void* d_ws, size_t ws_size,
                              hipStream_t stream)
{
    const float* user_feat = (const float*)d_in[0];
    const float* repo_feat = (const float*)d_in[1];
    const float* W_ue  = (const float*)d_in[2];   const float* b_ue  = (const float*)d_in[3];
    const float* W_re  = (const float*)d_in[4];   const float* b_re  = (const float*)d_in[5];
    const float* W_hur = (const float*)d_in[6];   const float* b_hur = (const float*)d_in[7];
    const float* W_hru = (const float*)d_in[8];   const float* b_hru = (const float*)d_in[9];
    const float* W_our = (const float*)d_in[10];  const float* b_our = (const float*)d_in[11];
    const float* W_oru = (const float*)d_in[12];  const float* b_oru = (const float*)d_in[13];
    const float* W_hcu = (const float*)d_in[14];  const float* b_hcu = (const float*)d_in[15];
    const float* W_hcr = (const float*)d_in[16];  const float* b_hcr = (const float*)d_in[17];
    const float* W_ocu = (const float*)d_in[18];  const float* b_ocu = (const float*)d_in[19];
    const float* W_ocr = (const float*)d_in[20];  const float* b_ocr = (const float*)d_in[21];
    const int* e_ur_src = (const int*)d_in[22];
    const int* e_ur_dst = (const int*)d_in[23];
    const int* e_ru_src = (const int*)d_in[24];
    const int* e_ru_dst = (const int*)d_in[25];
    const int* pos_u = (const int*)d_in[26];
    const int* pos_r = (const int*)d_in[27];
    const int* neg_u = (const int*)d_in[28];
    const int* neg_r = (const int*)d_in[29];

    // ---- workspace bump allocator (256-B aligned) ----
    char* base = (char*)d_ws;
    size_t cur = 0;
    auto alloc = [&](size_t bytes) {
        cur = (cur + 255) & ~(size_t)255;
        char* p = base + cur;
        cur += bytes;
        return p;
    };
    unsigned short* hU  = (unsigned short*)alloc((size_t)N_USER * D_EMB_P * 2); // h_user bf16
    unsigned short* hR  = (unsigned short*)alloc((size_t)N_REPO * D_EMB_P * 2); // h_repo bf16
    unsigned short* Cbuf= (unsigned short*)alloc((size_t)N_REPO * D_HID * 2);   // conv feat bf16 (max)
    unsigned short* Fb  = (unsigned short*)alloc((size_t)N_USER * D_HID * 2);   // out_user bf16
    unsigned short* Gb  = (unsigned short*)alloc((size_t)N_REPO * D_HID * 2);   // out_repo bf16
    float* Dmsg = (float*)alloc((size_t)N_USER * D_HID * 4);                    // msg->user fp32 (max)
    float* Emsg = (float*)alloc((size_t)N_REPO * D_HID * 4);                    // msg->repo fp32 (max)
    float* hUn  = (float*)alloc((size_t)N_USER * D_OUT * 4);                    // h_user_new fp32
    float* hRn  = (float*)alloc((size_t)N_REPO * D_OUT * 4);                    // h_repo_new fp32
    float* RS   = (float*)alloc(300000 * 4);
    float* rs_ur_src = RS;                  // user out-deg (ur) [50000]
    float* rs_ur_dst = RS + N_USER;         // repo in-deg  (ur) [100000]
    float* rs_ru_src = rs_ur_dst + N_REPO;  // repo out-deg (ru) [100000]
    float* rs_ru_dst = rs_ru_src + N_REPO;  // user in-deg  (ru) [50000]
    int* CNT = (int*)alloc(300000 * 4);
    int* cnt_ur_src = CNT;
    int* cnt_ur_dst = CNT + N_USER;
    int* cnt_ru_src = cnt_ur_dst + N_REPO;
    int* cnt_ru_dst = cnt_ru_src + N_REPO;
    int* off_ur = (int*)alloc((N_REPO + 1) * 4);
    int* off_ru = (int*)alloc((N_USER + 1) * 4);
    int* cur_ur = (int*)alloc(N_REPO * 4);
    int* cur_ru = (int*)alloc(N_USER * 4);
    int* bs_ur  = (int*)alloc(512 * 4);
    int* bs_ru  = (int*)alloc(512 * 4);
    int* csr_ur = (int*)alloc((size_t)NEDGE * 4);
    int* csr_ru = (int*)alloc((size_t)NEDGE * 4);
    unsigned short* WTue  = (unsigned short*)alloc(D_EMB_P * D_IN * 2);
    unsigned short* WTre  = (unsigned short*)alloc(D_EMB_P * D_IN * 2);
    unsigned short* WThur = (unsigned short*)alloc(D_HID * D_EMB_P * 2);
    unsigned short* WThru = (unsigned short*)alloc(D_HID * D_EMB_P * 2);
    unsigned short* WThcu = (unsigned short*)alloc(D_HID * D_EMB_P * 2);
    unsigned short* WThcr = (unsigned short*)alloc(D_HID * D_EMB_P * 2);
    unsigned short* WTour = (unsigned short*)alloc(D_OUT * D_HID * 2);
    unsigned short* WToru = (unsigned short*)alloc(D_OUT * D_HID * 2);
    unsigned short* WTocu = (unsigned short*)alloc(D_OUT * D_HID * 2);
    unsigned short* WTocr = (unsigned short*)alloc(D_OUT * D_HID * 2);

    const int BLK = 256;
    auto grid1 = [&](long n) { return dim3((unsigned)((n + BLK - 1) / BLK)); };

    // ---- weight conversion (transposed, padded, bf16) ----
    auto wc = [&](const float* W, unsigned short* WT, int K, int N, int Kp, int Np) {
        wconv<<<grid1((long)Kp * Np), BLK, 0, stream>>>(W, WT, K, N, Kp, Np);
    };
    wc(W_ue,  WTue,  D_IN, D_EMB, D_IN, D_EMB_P);
    wc(W_re,  WTre,  D_IN, D_EMB, D_IN, D_EMB_P);
    wc(W_hur, WThur, D_EMB, D_HID, D_EMB_P, D_HID);
    wc(W_hru, WThru, D_EMB, D_HID, D_EMB_P, D_HID);
    wc(W_hcu, WThcu, D_EMB, D_HID, D_EMB_P, D_HID);
    wc(W_hcr, WThcr, D_EMB, D_HID, D_EMB_P, D_HID);
    wc(W_our, WTour, D_HID, D_OUT, D_HID, D_OUT);
    wc(W_oru, WToru, D_HID, D_OUT, D_HID, D_OUT);
    wc(W_ocu, WTocu, D_HID, D_OUT, D_HID, D_OUT);
    wc(W_ocr, WTocr, D_HID, D_OUT, D_HID, D_OUT);

    // ---- degrees + CSR ----
    hipMemsetAsync(CNT, 0, 300000 * sizeof(int), stream);
    hist2<<<grid1(NEDGE), BLK, 0, stream>>>(e_ur_src, e_ur_dst, cnt_ur_src, cnt_ur_dst, NEDGE);
    hist2<<<grid1(NEDGE), BLK, 0, stream>>>(e_ru_src, e_ru_dst, cnt_ru_src, cnt_ru_dst, NEDGE);
    rsqrt_int<<<grid1(300000), BLK, 0, stream>>>(CNT, RS, 300000);
    {
        int nb = (N_REPO + 255) / 256;
        scan_block<<<nb, 256, 0, stream>>>(cnt_ur_dst, off_ur, bs_ur, N_REPO);
        scan_sums<<<1, 512, 0, stream>>>(bs_ur, nb);
        scan_fix<<<grid1(N_REPO + 1), 256, 0, stream>>>(off_ur, bs_ur, N_REPO, NEDGE);
    }
    {
        int nb = (N_USER + 255) / 256;
        scan_block<<<nb, 256, 0, stream>>>(cnt_ru_dst, off_ru, bs_ru, N_USER);
        scan_sums<<<1, 512, 0, stream>>>(bs_ru, nb);
        scan_fix<<<grid1(N_USER + 1), 256, 0, stream>>>(off_ru, bs_ru, N_USER, NEDGE);
    }
    hipMemcpyAsync(cur_ur, off_ur, N_REPO * sizeof(int), hipMemcpyDeviceToDevice, stream);
    hipMemcpyAsync(cur_ru, off_ru, N_USER * sizeof(int), hipMemcpyDeviceToDevice, stream);
    fill_csr<<<grid1(NEDGE), BLK, 0, stream>>>(e_ur_src, e_ur_dst, cur_ur, csr_ur, NEDGE);
    fill_csr<<<grid1(NEDGE), BLK, 0, stream>>>(e_ru_src, e_ru_dst, cur_ru, csr_ru, NEDGE);

    auto segsum = [&](const unsigned short* feat, const int* csr, const int* off,
                      float* agg, int n_dst, int D) {
        int d8 = D / 8;
        int nb = 256 / d8;
        segment_sum_bf16<<<(n_dst + nb - 1) / nb, 256, 0, stream>>>(feat, csr, off, agg,
                                                                    n_dst, d8, nb);
    };
    auto gblocks = [&](int M) { return dim3((unsigned)((M + 127) / 128)); };

    // ---- embeddings: fp32 A, bf16-out only ----
    gemm_mfma<D_EMB_P, false><<<gblocks(N_USER), 256, 0, stream>>>(
        user_feat, nullptr, WTue, b_ue, nullptr, nullptr, nullptr, nullptr,
        nullptr, hU, N_USER, D_EMB, D_IN, 0);
    gemm_mfma<D_EMB_P, false><<<gblocks(N_REPO), 256, 0, stream>>>(
        repo_feat, nullptr, WTre, b_re, nullptr, nullptr, nullptr, nullptr,
        nullptr, hR, N_REPO, D_EMB, D_IN, 0);

    // ---- hidden conv ru (repo->user): feat = (hR .* rs_ru_src) @ W_hru ----
    gemm_mfma<D_HID, true><<<gblocks(N_REPO), 256, 0, stream>>>(
        nullptr, hR, WThru, nullptr, rs_ru_src, nullptr, nullptr, nullptr,
        nullptr, Cbuf, N_REPO, D_HID, D_EMB_P, 0);
    segsum(Cbuf, csr_ru, off_ru, Dmsg, N_USER, D_HID);

    // ---- hidden conv ur (user->repo) ----
    gemm_mfma<D_HID, true><<<gblocks(N_USER), 256, 0, stream>>>(
        nullptr, hU, WThur, nullptr, rs_ur_src, nullptr, nullptr, nullptr,
        nullptr, Cbuf, N_USER, D_HID, D_EMB_P, 0);
    segsum(Cbuf, csr_ur, off_ur, Emsg, N_REPO, D_HID);

    // ---- residual + relu ----
    gemm_mfma<D_HID, true><<<gblocks(N_USER), 256, 0, stream>>>(
        nullptr, hU, WThcu, b_hcu, nullptr, Dmsg, rs_ru_dst, b_hru,
        nullptr, Fb, N_USER, D_HID, D_EMB_P, 1);
    gemm_mfma<D_HID, true><<<gblocks(N_REPO), 256, 0, stream>>>(
        nullptr, hR, WThcr, b_hcr, nullptr, Emsg, rs_ur_dst, b_hur,
        nullptr, Gb, N_REPO, D_HID, D_EMB_P, 1);

    // ---- output conv ru ----
    gemm_mfma<D_OUT, true><<<gblocks(N_REPO), 256, 0, stream>>>(
        nullptr, Gb, WToru, nullptr, rs_ru_src, nullptr, nullptr, nullptr,
        nullptr, Cbuf, N_REPO, D_OUT, D_HID, 0);
    segsum(Cbuf, csr_ru, off_ru, Dmsg, N_USER, D_OUT);

    // ---- output conv ur ----
    gemm_mfma<D_OUT, true><<<gblocks(N_USER), 256, 0, stream>>>(
        nullptr, Fb, WTour, nullptr, rs_ur_src, nullptr, nullptr, nullptr,
        nullptr, Cbuf, N_USER, D_OUT, D_HID, 0);
    segsum(Cbuf, csr_ur, off_ur, Emsg, N_REPO, D_OUT);

    // ---- final nodes (fp32 out) ----
    gemm_mfma<D_OUT, true><<<gblocks(N_USER), 256, 0, stream>>>(
        nullptr, Fb, WTocu, b_ocu, nullptr, Dmsg, rs_ru_dst, b_oru,
        hUn, nullptr, N_USER, D_OUT, D_HID, 1);
    gemm_mfma<D_OUT, true><<<gblocks(N_REPO), 256, 0, stream>>>(
        nullptr, Gb, WTocr, b_ocr, nullptr, Emsg, rs_ur_dst, b_our,
        hRn, nullptr, N_REPO, D_OUT, D_HID, 1);

    normalize_rows64<<<grid1((long)N_USER * 64), BLK, 0, stream>>>(hUn, N_USER);
    normalize_rows64<<<grid1((long)N_REPO * 64), BLK, 0, stream>>>(hRn, N_REPO);

    float* out = (float*)d_out;
    score_pairs<<<grid1((long)NPAIR * 64), BLK, 0, stream>>>(hUn, hRn, pos_u, pos_r, out, NPAIR);
    score_pairs<<<grid1((long)NPAIR * 64), BLK, 0, stream>>>(hUn, hRn, neg_u, neg_r, out + NPAIR, NPAIR);
}

// Round 5
// 918.756 us; speedup vs baseline: 5.9732x; 1.2000x over previous
//
#include <hip/hip_runtime.h>
#include <hip/hip_bf16.h>

// Model sizes
#define N_USER 50000
#define N_REPO 100000
#define NEDGE  1000000
#define NPAIR  200000
#define D_IN   256
#define D_EMB  125
#define D_HID  96
#define D_OUT  64

typedef short bf16x8 __attribute__((ext_vector_type(8)));
typedef float f32x4 __attribute__((ext_vector_type(4)));
typedef unsigned short ushort8 __attribute__((ext_vector_type(8)));

__device__ __forceinline__ unsigned short f2bf(float x) {
    union { float f; unsigned u; } c; c.f = x;
    unsigned r = c.u + 0x7fffu + ((c.u >> 16) & 1u);
    return (unsigned short)(r >> 16);
}
__device__ __forceinline__ float bf2f(unsigned short b) {
    union { unsigned u; float f; } c; c.u = ((unsigned)b) << 16;
    return c.f;
}

// ---------------------------------------------------------------------------
// Fused weight convert: all 10 weights -> bf16, transposed [N][K], padded,
// with K-concatenation for the fused conv GEMMs. One dispatch.
// Arena layout (shorts):
//   WTue  @ 0      [128][256]
//   WTre  @ 32768  [128][256]
//   WTcat_u @ 65536  [96][256]  (k 0..127: W_hcu, k 128..255: W_hru)
//   WTcat_r @ 90112  [96][256]  (W_hcr | W_hur)
//   WTcat2_u @ 114688 [64][192] (W_ocu | W_oru)
//   WTcat2_r @ 126976 [64][192] (W_ocr | W_our)
// total 139264 shorts
__global__ void wconv_all(const float* W0, const float* W1, const float* W2,
                          const float* W3, const float* W4, const float* W5,
                          const float* W6, const float* W7, const float* W8,
                          const float* W9, unsigned short* __restrict__ arena)
{
    int idx = blockIdx.x * 256 + threadIdx.x;
    if (idx >= 139264) return;
    const int cum[11]   = {0, 32768, 65536, 77824, 90112, 102400, 114688, 120832, 126976, 133120, 139264};
    const int dstoff[10]= {0, 32768, 65536, 65536, 90112, 90112, 114688, 114688, 126976, 126976};
    const int Kd[10]    = {256, 256, 256, 256, 256, 256, 192, 192, 192, 192};
    const int koff[10]  = {0, 0, 0, 128, 0, 128, 0, 96, 0, 96};
    const int Kdseg[10] = {256, 256, 128, 128, 128, 128, 96, 96, 96, 96};
    const int Ksrc[10]  = {256, 256, 125, 125, 125, 125, 96, 96, 96, 96};
    const int Nsrc[10]  = {125, 125, 96, 96, 96, 96, 64, 64, 64, 64};
    const float* Ws[10] = {W0, W1, W2, W3, W4, W5, W6, W7, W8, W9};
    int s = 0;
    #pragma unroll
    for (int i = 1; i < 10; ++i) if (idx >= cum[i]) s = i;
    int rem = idx - cum[s];
    int n = rem / Kdseg[s], k = rem - n * Kdseg[s];
    float v = (k < Ksrc[s] && n < Nsrc[s]) ? Ws[s][(size_t)k * Nsrc[s] + n] : 0.0f;
    arena[(size_t)dstoff[s] + (size_t)n * Kd[s] + koff[s] + k] = f2bf(v);
}

// ---------------------------------------------------------------------------
// CSR build (both graphs fused per phase)
// ---------------------------------------------------------------------------
__global__ void hist_all(const int* __restrict__ us, const int* __restrict__ ud,
                         const int* __restrict__ rs, const int* __restrict__ rd,
                         int* __restrict__ c_ur_s, int* __restrict__ c_ur_d,
                         int* __restrict__ c_ru_s, int* __restrict__ c_ru_d)
{
    int e = blockIdx.x * 256 + threadIdx.x;
    if (e < NEDGE) {
        atomicAdd(&c_ur_s[us[e]], 1);
        atomicAdd(&c_ur_d[ud[e]], 1);
    } else if (e < 2 * NEDGE) {
        int i = e - NEDGE;
        atomicAdd(&c_ru_s[rs[i]], 1);
        atomicAdd(&c_ru_d[rd[i]], 1);
    }
}

__global__ void rsqrt_int(const int* __restrict__ cnt, float* __restrict__ rs, int n)
{
    int i = blockIdx.x * 256 + threadIdx.x;
    if (i >= n) return;
    rs[i] = rsqrtf((float)max(cnt[i], 1));
}

#define NBU 391  // ceil(N_REPO/256)
#define NBR 196  // ceil(N_USER/256)

__global__ void scan_block_all(const int* __restrict__ cnt_ur, int* __restrict__ off_ur,
                               int* __restrict__ bs_ur,
                               const int* __restrict__ cnt_ru, int* __restrict__ off_ru,
                               int* __restrict__ bs_ru)
{
    __shared__ int s[256];
    int b = blockIdx.x;
    const int* cnt; int* off; int* bs; int n, bi;
    if (b < NBU) { cnt = cnt_ur; off = off_ur; bs = bs_ur; n = N_REPO; bi = b; }
    else { cnt = cnt_ru; off = off_ru; bs = bs_ru; n = N_USER; bi = b - NBU; }
    int t = threadIdx.x, i = bi * 256 + t;
    int v = (i < n) ? cnt[i] : 0;
    s[t] = v;
    __syncthreads();
    for (int d = 1; d < 256; d <<= 1) {
        int u = (t >= d) ? s[t - d] : 0;
        __syncthreads();
        s[t] += u;
        __syncthreads();
    }
    if (i < n) off[i] = s[t] - v;
    if (t == 255) bs[bi] = s[255];
}

__global__ void scan_sums2(int* __restrict__ bs_ur, int* __restrict__ bs_ru)
{
    __shared__ int s[512];
    int* b = (blockIdx.x == 0) ? bs_ur : bs_ru;
    int nb = (blockIdx.x == 0) ? NBU : NBR;
    int t = threadIdx.x;
    s[t] = (t < nb) ? b[t] : 0;
    __syncthreads();
    for (int d = 1; d < 512; d <<= 1) {
        int v = (t >= d) ? s[t - d] : 0;
        __syncthreads();
        s[t] += v;
        __syncthreads();
    }
    if (t < nb) b[t] = s[t];
}

__global__ void scan_fix_all(int* __restrict__ off_ur, int* __restrict__ cur_ur,
                             const int* __restrict__ bs_ur,
                             int* __restrict__ off_ru, int* __restrict__ cur_ru,
                             const int* __restrict__ bs_ru)
{
    int i = blockIdx.x * 256 + threadIdx.x;
    if (i <= N_REPO) {
        if (i == N_REPO) off_ur[i] = NEDGE;
        else {
            int blk = i >> 8;
            int v = off_ur[i] + (blk > 0 ? bs_ur[blk - 1] : 0);
            off_ur[i] = v;
            cur_ur[i] = v;
        }
    }
    int j = i - (N_REPO + 1);
    if (j >= 0 && j <= N_USER) {
        if (j == N_USER) off_ru[j] = NEDGE;
        else {
            int blk = j >> 8;
            int v = off_ru[j] + (blk > 0 ? bs_ru[blk - 1] : 0);
            off_ru[j] = v;
            cur_ru[j] = v;
        }
    }
}

__global__ void fill_all(const int* __restrict__ us, const int* __restrict__ ud,
                         const int* __restrict__ rs, const int* __restrict__ rd,
                         int* __restrict__ cur_ur, int* __restrict__ csr_ur,
                         int* __restrict__ cur_ru, int* __restrict__ csr_ru)
{
    int e = blockIdx.x * 256 + threadIdx.x;
    if (e < NEDGE) {
        int p = atomicAdd(&cur_ur[ud[e]], 1);
        csr_ur[p] = us[e];
    } else if (e < 2 * NEDGE) {
        int i = e - NEDGE;
        int p = atomicAdd(&cur_ru[rd[i]], 1);
        csr_ru[p] = rs[i];
    }
}

// ---------------------------------------------------------------------------
// bf16 MFMA GEMM: BM=64, BN=NP, BK=32, 4 waves (2x2), double-buffered LDS
// with register prefetch. C = op(A @ WT^T + bias1 + bias2), fp32 and/or
// bf16 strided output. A fp32 (ABF=false) or bf16 (ABF=true), row stride lda.
// ---------------------------------------------------------------------------
template<int NP, bool ABF>
__global__ __launch_bounds__(256) void gemm_mfma(
    const float* __restrict__ Af, const unsigned short* __restrict__ Ab, int lda,
    const unsigned short* __restrict__ WT,  // [NP][K] bf16
    const float* __restrict__ bias1, const float* __restrict__ bias2,
    float* __restrict__ Cf, unsigned short* __restrict__ Cb, int ldc,
    int M, int Nreal, int K, int relu)
{
    constexpr int NF = NP / 32;                 // 16-col frags per wave
    constexpr int BCH = (NP * 4 + 255) / 256;   // B staging chunks per thread
    __shared__ unsigned short As[2][64 * 40];
    __shared__ unsigned short Bs[2][NP * 40];
    const int t = threadIdx.x;
    const int row0 = blockIdx.x * 64;
    const int w = t >> 6, l = t & 63;
    const int wr = w >> 1, wc = w & 1;
    const int lr = l & 15, q = l >> 4;
    const int ar = t >> 2, akq = t & 3;
    const int grow = row0 + ar;

    f32x4 acc[2][NF];
    #pragma unroll
    for (int m = 0; m < 2; ++m)
        #pragma unroll
        for (int n = 0; n < NF; ++n)
            acc[m][n] = (f32x4){0.f, 0.f, 0.f, 0.f};

    float afr[8];
    ushort8 ab0;
    ushort8 bb[BCH];

    auto loadTile = [&](int k0) {
        if (grow < M) {
            if (ABF) {
                ab0 = *(const ushort8*)(Ab + (size_t)grow * lda + k0 + akq * 8);
            } else {
                const float* p = Af + (size_t)grow * lda + k0 + akq * 8;
                ((float4*)afr)[0] = *(const float4*)p;
                ((float4*)afr)[1] = *(const float4*)(p + 4);
            }
        } else {
            if (ABF) {
                #pragma unroll
                for (int i = 0; i < 8; ++i) ab0[i] = 0;
            } else {
                #pragma unroll
                for (int i = 0; i < 8; ++i) afr[i] = 0.f;
            }
        }
        #pragma unroll
        for (int ch = 0; ch < BCH; ++ch) {
            int cid = t + ch * 256;
            if ((NP * 4) % 256 == 0 || cid < NP * 4) {
                int c = cid >> 2, kq = cid & 3;
                bb[ch] = *(const ushort8*)(WT + (size_t)c * K + k0 + kq * 8);
            }
        }
    };
    auto storeTile = [&](int buf) {
        ushort8 o;
        if (ABF) o = ab0;
        else {
            #pragma unroll
            for (int i = 0; i < 8; ++i) o[i] = f2bf(afr[i]);
        }
        *(ushort8*)(&As[buf][ar * 40 + akq * 8]) = o;
        #pragma unroll
        for (int ch = 0; ch < BCH; ++ch) {
            int cid = t + ch * 256;
            if ((NP * 4) % 256 == 0 || cid < NP * 4) {
                int c = cid >> 2, kq = cid & 3;
                *(ushort8*)(&Bs[buf][c * 40 + kq * 8]) = bb[ch];
            }
        }
    };

    loadTile(0);
    storeTile(0);
    __syncthreads();
    const int nIter = K >> 5;
    for (int it = 0; it < nIter; ++it) {
        const int cur = it & 1;
        if (it + 1 < nIter) loadTile((it + 1) << 5);  // prefetch overlaps compute
        bf16x8 a[2], b[NF];
        #pragma unroll
        for (int m = 0; m < 2; ++m)
            a[m] = *(const bf16x8*)(&As[cur][(wr * 32 + m * 16 + lr) * 40 + q * 8]);
        #pragma unroll
        for (int n = 0; n < NF; ++n)
            b[n] = *(const bf16x8*)(&Bs[cur][(wc * (NP / 2) + n * 16 + lr) * 40 + q * 8]);
        #pragma unroll
        for (int m = 0; m < 2; ++m)
            #pragma unroll
            for (int n = 0; n < NF; ++n)
                acc[m][n] = __builtin_amdgcn_mfma_f32_16x16x32_bf16(a[m], b[n], acc[m][n], 0, 0, 0);
        __syncthreads();
        if (it + 1 < nIter) storeTile(cur ^ 1);
        __syncthreads();
    }

    #pragma unroll
    for (int m = 0; m < 2; ++m) {
        #pragma unroll
        for (int j = 0; j < 4; ++j) {
            int r = row0 + wr * 32 + m * 16 + q * 4 + j;
            if (r >= M) continue;
            #pragma unroll
            for (int n = 0; n < NF; ++n) {
                int c = wc * (NP / 2) + n * 16 + lr;
                float v = acc[m][n][j];
                if (c < Nreal) {
                    if (bias1) v += bias1[c];
                    if (bias2) v += bias2[c];
                    if (relu) v = fmaxf(v, 0.f);
                    if (Cf) Cf[(size_t)r * ldc + c] = v;
                } else {
                    v = 0.f;
                }
                if (Cb) Cb[(size_t)r * ldc + c] = f2bf(v);
            }
        }
    }
}

// ---------------------------------------------------------------------------
// Pull segment-sum in embedding space: dst[node] = rs_d[node] * sum_{e}
// src[csr[e]] * rs_s[csr[e]], bf16 in/out, fp32 accumulate. Strided I/O.
// Thread = (node, 8-col chunk).
// ---------------------------------------------------------------------------
__global__ void segsum(const unsigned short* __restrict__ src, int lds_,
                       const int* __restrict__ csr, const int* __restrict__ off,
                       const float* __restrict__ rs_s, const float* __restrict__ rs_d,
                       unsigned short* __restrict__ dst, int ldd, int coff,
                       int n_dst, int d8, int nb)
{
    int ni = threadIdx.x / d8;
    int c8 = threadIdx.x - ni * d8;
    if (ni >= nb) return;
    int node = blockIdx.x * nb + ni;
    if (node >= n_dst) return;
    int j0 = off[node], j1 = off[node + 1];
    float acc[8] = {};
    for (int j = j0; j < j1; ++j) {
        int s = csr[j];
        float sc = rs_s[s];
        ushort8 v = *(const ushort8*)(src + (size_t)s * lds_ + c8 * 8);
        #pragma unroll
        for (int i = 0; i < 8; ++i) acc[i] += bf2f(v[i]) * sc;
    }
    float sd = rs_d[node];
    ushort8 o;
    #pragma unroll
    for (int i = 0; i < 8; ++i) o[i] = f2bf(acc[i] * sd);
    *(ushort8*)(dst + (size_t)node * ldd + coff + c8 * 8) = o;
}

// ---------------------------------------------------------------------------
// Normalize rows of hU [nU x 64] and hR [nR x 64] in one dispatch; wave/row.
// ---------------------------------------------------------------------------
__global__ void norm_all(float* __restrict__ hU, float* __restrict__ hR)
{
    int g = (blockIdx.x * 256 + threadIdx.x) >> 6;
    int lane = threadIdx.x & 63;
    float* h;
    int row;
    if (g < N_USER) { h = hU; row = g; }
    else if (g < N_USER + N_REPO) { h = hR; row = g - N_USER; }
    else return;
    float v = h[(size_t)row * 64 + lane];
    float s = v * v;
    #pragma unroll
    for (int off = 32; off; off >>= 1) s += __shfl_xor(s, off);
    float nrm = fmaxf(sqrtf(s), 1e-12f);
    h[(size_t)row * 64 + lane] = v / nrm;
}

// ---------------------------------------------------------------------------
// Both score sets in one dispatch; 16 lanes per pair, float4 per lane.
// ---------------------------------------------------------------------------
__global__ void score_all(const float* __restrict__ nu, const float* __restrict__ nr,
                          const int* __restrict__ pu, const int* __restrict__ pr,
                          const int* __restrict__ qu, const int* __restrict__ qr,
                          float* __restrict__ out)
{
    int tid = blockIdx.x * 256 + threadIdx.x;
    int pair = tid >> 4, sl = tid & 15;
    if (pair >= 2 * NPAIR) return;
    int g = (pair < NPAIR) ? pair : pair - NPAIR;
    int iu = (pair < NPAIR) ? pu[g] : qu[g];
    int ir = (pair < NPAIR) ? pr[g] : qr[g];
    float4 a = *(const float4*)(nu + (size_t)iu * 64 + sl * 4);
    float4 b = *(const float4*)(nr + (size_t)ir * 64 + sl * 4);
    float s = a.x * b.x + a.y * b.y + a.z * b.z + a.w * b.w;
    s += __shfl_xor(s, 1);
    s += __shfl_xor(s, 2);
    s += __shfl_xor(s, 4);
    s += __shfl_xor(s, 8);
    if (sl == 0) out[pair] = s;
}

// ---------------------------------------------------------------------------
extern "C" void kernel_launch(void* const* d_in, const int* in_sizes, int n_in,
                              void* d_out, int out_size, void* d_ws, size_t ws_size,
                              hipStream_t stream)
{
    const float* user_feat = (const float*)d_in[0];
    const float* repo_feat = (const float*)d_in[1];
    const float* W_ue  = (const float*)d_in[2];   const float* b_ue  = (const float*)d_in[3];
    const float* W_re  = (const float*)d_in[4];   const float* b_re  = (const float*)d_in[5];
    const float* W_hur = (const float*)d_in[6];   const float* b_hur = (const float*)d_in[7];
    const float* W_hru = (const float*)d_in[8];   const float* b_hru = (const float*)d_in[9];
    const float* W_our = (const float*)d_in[10];  const float* b_our = (const float*)d_in[11];
    const float* W_oru = (const float*)d_in[12];  const float* b_oru = (const float*)d_in[13];
    const float* W_hcu = (const float*)d_in[14];  const float* b_hcu = (const float*)d_in[15];
    const float* W_hcr = (const float*)d_in[16];  const float* b_hcr = (const float*)d_in[17];
    const float* W_ocu = (const float*)d_in[18];  const float* b_ocu = (const float*)d_in[19];
    const float* W_ocr = (const float*)d_in[20];  const float* b_ocr = (const float*)d_in[21];
    const int* e_ur_src = (const int*)d_in[22];
    const int* e_ur_dst = (const int*)d_in[23];
    const int* e_ru_src = (const int*)d_in[24];
    const int* e_ru_dst = (const int*)d_in[25];
    const int* pos_u = (const int*)d_in[26];
    const int* pos_r = (const int*)d_in[27];
    const int* neg_u = (const int*)d_in[28];
    const int* neg_r = (const int*)d_in[29];

    char* base = (char*)d_ws;
    size_t cur = 0;
    auto alloc = [&](size_t bytes) {
        cur = (cur + 255) & ~(size_t)255;
        char* p = base + cur;
        cur += bytes;
        return p;
    };
    // cat buffers: [h | agg] along K
    unsigned short* hUcat = (unsigned short*)alloc((size_t)N_USER * 256 * 2);
    unsigned short* hRcat = (unsigned short*)alloc((size_t)N_REPO * 256 * 2);
    unsigned short* Fcat  = (unsigned short*)alloc((size_t)N_USER * 192 * 2);
    unsigned short* Gcat  = (unsigned short*)alloc((size_t)N_REPO * 192 * 2);
    float* hUn = (float*)alloc((size_t)N_USER * 64 * 4);
    float* hRn = (float*)alloc((size_t)N_REPO * 64 * 4);
    float* RS  = (float*)alloc(300000 * 4);
    float* rs_ur_src = RS;
    float* rs_ur_dst = RS + N_USER;
    float* rs_ru_src = rs_ur_dst + N_REPO;
    float* rs_ru_dst = rs_ru_src + N_REPO;
    int* CNT = (int*)alloc(300000 * 4);
    int* cnt_ur_src = CNT;
    int* cnt_ur_dst = CNT + N_USER;
    int* cnt_ru_src = cnt_ur_dst + N_REPO;
    int* cnt_ru_dst = cnt_ru_src + N_REPO;
    int* off_ur = (int*)alloc((N_REPO + 1) * 4);
    int* off_ru = (int*)alloc((N_USER + 1) * 4);
    int* cur_ur = (int*)alloc(N_REPO * 4);
    int* cur_ru = (int*)alloc(N_USER * 4);
    int* bs_ur  = (int*)alloc(512 * 4);
    int* bs_ru  = (int*)alloc(512 * 4);
    int* csr_ur = (int*)alloc((size_t)NEDGE * 4);
    int* csr_ru = (int*)alloc((size_t)NEDGE * 4);
    unsigned short* WTarena = (unsigned short*)alloc(139264 * 2);
    unsigned short* WTue    = WTarena;
    unsigned short* WTre    = WTarena + 32768;
    unsigned short* WTcat_u = WTarena + 65536;
    unsigned short* WTcat_r = WTarena + 90112;
    unsigned short* WTo_u   = WTarena + 114688;
    unsigned short* WTo_r   = WTarena + 126976;

    auto grid1 = [&](long n) { return dim3((unsigned)((n + 255) / 256)); };

    // ---- weights (1 dispatch) ----
    wconv_all<<<grid1(139264), 256, 0, stream>>>(
        W_ue, W_re, W_hcu, W_hru, W_hcr, W_hur, W_ocu, W_oru, W_ocr, W_our, WTarena);

    // ---- CSR build ----
    hipMemsetAsync(CNT, 0, 300000 * sizeof(int), stream);
    hist_all<<<grid1(2L * NEDGE), 256, 0, stream>>>(
        e_ur_src, e_ur_dst, e_ru_src, e_ru_dst,
        cnt_ur_src, cnt_ur_dst, cnt_ru_src, cnt_ru_dst);
    rsqrt_int<<<grid1(300000), 256, 0, stream>>>(CNT, RS, 300000);
    scan_block_all<<<NBU + NBR, 256, 0, stream>>>(cnt_ur_dst, off_ur, bs_ur,
                                                  cnt_ru_dst, off_ru, bs_ru);
    scan_sums2<<<2, 512, 0, stream>>>(bs_ur, bs_ru);
    scan_fix_all<<<grid1(N_REPO + 1 + N_USER + 1), 256, 0, stream>>>(
        off_ur, cur_ur, bs_ur, off_ru, cur_ru, bs_ru);
    fill_all<<<grid1(2L * NEDGE), 256, 0, stream>>>(
        e_ur_src, e_ur_dst, e_ru_src, e_ru_dst, cur_ur, csr_ur, cur_ru, csr_ru);

    auto gb = [&](int M) { return dim3((unsigned)((M + 63) / 64)); };

    // ---- embeddings: hUcat[:,0:128] = user_feat @ W_ue + b_ue ----
    gemm_mfma<128, false><<<gb(N_USER), 256, 0, stream>>>(
        user_feat, nullptr, 256, WTue, b_ue, nullptr,
        nullptr, hUcat, 256, N_USER, D_EMB, D_IN, 0);
    gemm_mfma<128, false><<<gb(N_REPO), 256, 0, stream>>>(
        repo_feat, nullptr, 256, WTre, b_re, nullptr,
        nullptr, hRcat, 256, N_REPO, D_EMB, D_IN, 0);

    // ---- aggregate embeddings (conv msg in embedding space) ----
    // agg_u = rs_ru_dst .* segsum(hR .* rs_ru_src)  -> hUcat[:,128:256]
    segsum<<<dim3((N_USER + 15) / 16), 256, 0, stream>>>(
        hRcat, 256, csr_ru, off_ru, rs_ru_src, rs_ru_dst,
        hUcat, 256, 128, N_USER, 16, 16);
    // agg_r -> hRcat[:,128:256]
    segsum<<<dim3((N_REPO + 15) / 16), 256, 0, stream>>>(
        hUcat, 256, csr_ur, off_ur, rs_ur_src, rs_ur_dst,
        hRcat, 256, 128, N_REPO, 16, 16);

    // ---- hidden layer: F = relu([hU|agg_u] @ [W_hcu;W_hru] + b_hcu + b_hru) ----
    gemm_mfma<96, true><<<gb(N_USER), 256, 0, stream>>>(
        nullptr, hUcat, 256, WTcat_u, b_hcu, b_hru,
        nullptr, Fcat, 192, N_USER, D_HID, 256, 1);
    gemm_mfma<96, true><<<gb(N_REPO), 256, 0, stream>>>(
        nullptr, hRcat, 256, WTcat_r, b_hcr, b_hur,
        nullptr, Gcat, 192, N_REPO, D_HID, 256, 1);

    // ---- aggregate hidden ----
    segsum<<<dim3((N_USER + 20) / 21), 256, 0, stream>>>(
        Gcat, 192, csr_ru, off_ru, rs_ru_src, rs_ru_dst,
        Fcat, 192, 96, N_USER, 12, 21);
    segsum<<<dim3((N_REPO + 20) / 21), 256, 0, stream>>>(
        Fcat, 192, csr_ur, off_ur, rs_ur_src, rs_ur_dst,
        Gcat, 192, 96, N_REPO, 12, 21);

    // ---- output layer: hUn = relu([F|aggG_u] @ [W_ocu;W_oru] + b_ocu + b_oru) ----
    gemm_mfma<64, true><<<gb(N_USER), 256, 0, stream>>>(
        nullptr, Fcat, 192, WTo_u, b_ocu, b_oru,
        hUn, nullptr, 64, N_USER, D_OUT, 192, 1);
    gemm_mfma<64, true><<<gb(N_REPO), 256, 0, stream>>>(
        nullptr, Gcat, 192, WTo_r, b_ocr, b_our,
        hRn, nullptr, 64, N_REPO, D_OUT, 192, 1);

    // ---- normalize + score ----
    norm_all<<<grid1((long)(N_USER + N_REPO) * 64), 256, 0, stream>>>(hUn, hRn);
    score_all<<<grid1((long)2 * NPAIR * 16), 256, 0, stream>>>(
        hUn, hRn, pos_u, pos_r, neg_u, neg_r, (float*)d_out);
}

// Round 6
// 814.024 us; speedup vs baseline: 6.7417x; 1.1287x over previous
//
#include <hip/hip_runtime.h>
#include <hip/hip_bf16.h>

// Model sizes
#define N_USER 50000
#define N_REPO 100000
#define NEDGE  1000000
#define NPAIR  200000
#define D_IN   256
#define D_EMB  125
#define D_HID  96
#define D_OUT  64

// Block-partitioning constants
#define NBU 391    // ceil(N_REPO/256) scan blocks
#define NBR 196    // ceil(N_USER/256)
#define GBU 782    // ceil(N_USER/64) gemm blocks
#define GBR 1563   // ceil(N_REPO/64)
#define FILLB 7813 // ceil(2*NEDGE/256)
#define WCB 544    // ceil(139264/256) weight-convert blocks
#define SCB (NBU + NBR)
#define RSB 1172   // ceil(300000/256)

typedef short bf16x8 __attribute__((ext_vector_type(8)));
typedef float f32x4 __attribute__((ext_vector_type(4)));
typedef unsigned short ushort8 __attribute__((ext_vector_type(8)));

__device__ __forceinline__ unsigned short f2bf(float x) {
    union { float f; unsigned u; } c; c.f = x;
    unsigned r = c.u + 0x7fffu + ((c.u >> 16) & 1u);
    return (unsigned short)(r >> 16);
}
__device__ __forceinline__ float bf2f(unsigned short b) {
    union { unsigned u; float f; } c; c.u = ((unsigned)b) << 16;
    return c.f;
}

// ---------------------------------------------------------------------------
// prep: blocks [0,WCB) convert/transpose/pad all 10 weights into bf16 arena;
// blocks [WCB,..) histogram both edge lists (4 degree arrays).
// Arena (shorts): WTue@0 [128][256] | WTre@32768 | WTcat_u@65536 [96][256]
// (W_hcu|W_hru) | WTcat_r@90112 | WTo_u@114688 [64][192] (W_ocu|W_oru) |
// WTo_r@126976. total 139264.
// ---------------------------------------------------------------------------
__global__ __launch_bounds__(256) void prep(
    const float* W0, const float* W1, const float* W2, const float* W3,
    const float* W4, const float* W5, const float* W6, const float* W7,
    const float* W8, const float* W9, unsigned short* __restrict__ arena,
    const int* __restrict__ us, const int* __restrict__ ud,
    const int* __restrict__ rs, const int* __restrict__ rd,
    int* __restrict__ c_ur_s, int* __restrict__ c_ur_d,
    int* __restrict__ c_ru_s, int* __restrict__ c_ru_d)
{
    int b = blockIdx.x;
    if (b < WCB) {
        int idx = b * 256 + threadIdx.x;
        if (idx >= 139264) return;
        const int cum[11]   = {0, 32768, 65536, 77824, 90112, 102400, 114688, 120832, 126976, 133120, 139264};
        const int dstoff[10]= {0, 32768, 65536, 65536, 90112, 90112, 114688, 114688, 126976, 126976};
        const int Kd[10]    = {256, 256, 256, 256, 256, 256, 192, 192, 192, 192};
        const int koff[10]  = {0, 0, 0, 128, 0, 128, 0, 96, 0, 96};
        const int Kdseg[10] = {256, 256, 128, 128, 128, 128, 96, 96, 96, 96};
        const int Ksrc[10]  = {256, 256, 125, 125, 125, 125, 96, 96, 96, 96};
        const int Nsrc[10]  = {125, 125, 96, 96, 96, 96, 64, 64, 64, 64};
        const float* Ws[10] = {W0, W1, W2, W3, W4, W5, W6, W7, W8, W9};
        int s = 0;
        #pragma unroll
        for (int i = 1; i < 10; ++i) if (idx >= cum[i]) s = i;
        int rem = idx - cum[s];
        int n = rem / Kdseg[s], k = rem - n * Kdseg[s];
        float v = (k < Ksrc[s] && n < Nsrc[s]) ? Ws[s][(size_t)k * Nsrc[s] + n] : 0.0f;
        arena[(size_t)dstoff[s] + (size_t)n * Kd[s] + koff[s] + k] = f2bf(v);
    } else {
        int e = (b - WCB) * 256 + threadIdx.x;
        if (e < NEDGE) {
            atomicAdd(&c_ur_s[us[e]], 1);
            atomicAdd(&c_ur_d[ud[e]], 1);
        } else if (e < 2 * NEDGE) {
            int i = e - NEDGE;
            atomicAdd(&c_ru_s[rs[i]], 1);
            atomicAdd(&c_ru_d[rd[i]], 1);
        }
    }
}

// ---------------------------------------------------------------------------
// scan_a: blocks [0,SCB) per-block exclusive scan of dst counts; blocks
// [SCB,..) compute rsqrt-degree arrays from counts.
// ---------------------------------------------------------------------------
__global__ __launch_bounds__(256) void scan_a(
    const int* __restrict__ cnt_ur, int* __restrict__ off_ur, int* __restrict__ bs_ur,
    const int* __restrict__ cnt_ru, int* __restrict__ off_ru, int* __restrict__ bs_ru,
    const int* __restrict__ CNT, float* __restrict__ RS)
{
    int b = blockIdx.x;
    if (b < SCB) {
        __shared__ int s[256];
        const int* cnt; int* off; int* bs; int n, bi;
        if (b < NBU) { cnt = cnt_ur; off = off_ur; bs = bs_ur; n = N_REPO; bi = b; }
        else { cnt = cnt_ru; off = off_ru; bs = bs_ru; n = N_USER; bi = b - NBU; }
        int t = threadIdx.x, i = bi * 256 + t;
        int v = (i < n) ? cnt[i] : 0;
        s[t] = v;
        __syncthreads();
        for (int d = 1; d < 256; d <<= 1) {
            int u = (t >= d) ? s[t - d] : 0;
            __syncthreads();
            s[t] += u;
            __syncthreads();
        }
        if (i < n) off[i] = s[t] - v;
        if (t == 255) bs[bi] = s[255];
    } else {
        int i = (b - SCB) * 256 + threadIdx.x;
        if (i < 300000) RS[i] = rsqrtf((float)max(CNT[i], 1));
    }
}

__global__ void scan_sums2(int* __restrict__ bs_ur, int* __restrict__ bs_ru)
{
    __shared__ int s[512];
    int* b = (blockIdx.x == 0) ? bs_ur : bs_ru;
    int nb = (blockIdx.x == 0) ? NBU : NBR;
    int t = threadIdx.x;
    s[t] = (t < nb) ? b[t] : 0;
    __syncthreads();
    for (int d = 1; d < 512; d <<= 1) {
        int v = (t >= d) ? s[t - d] : 0;
        __syncthreads();
        s[t] += v;
        __syncthreads();
    }
    if (t < nb) b[t] = s[t];
}

__global__ void scan_fix_all(int* __restrict__ off_ur, int* __restrict__ cur_ur,
                             const int* __restrict__ bs_ur,
                             int* __restrict__ off_ru, int* __restrict__ cur_ru,
                             const int* __restrict__ bs_ru)
{
    int i = blockIdx.x * 256 + threadIdx.x;
    if (i <= N_REPO) {
        if (i == N_REPO) off_ur[i] = NEDGE;
        else {
            int blk = i >> 8;
            int v = off_ur[i] + (blk > 0 ? bs_ur[blk - 1] : 0);
            off_ur[i] = v;
            cur_ur[i] = v;
        }
    }
    int j = i - (N_REPO + 1);
    if (j >= 0 && j <= N_USER) {
        if (j == N_USER) off_ru[j] = NEDGE;
        else {
            int blk = j >> 8;
            int v = off_ru[j] + (blk > 0 ? bs_ru[blk - 1] : 0);
            off_ru[j] = v;
            cur_ru[j] = v;
        }
    }
}

// ---------------------------------------------------------------------------
// bf16 MFMA GEMM body: BM=64, BN=NP, BK=32, 4 waves (2x2), double-buffered
// LDS with register prefetch. C = op(A @ WT^T + bias1 + bias2).
// NORM: L2-normalize each 64-wide output row via LDS before writing (NP=64).
// As/Bs must be contiguous (one shared block) when NORM.
// ---------------------------------------------------------------------------
template<int NP, bool ABF, bool NORM>
__device__ __forceinline__ void gemm_body(
    unsigned short* __restrict__ As, unsigned short* __restrict__ Bs, int bx,
    const float* __restrict__ Af, const unsigned short* __restrict__ Ab, int lda,
    const unsigned short* __restrict__ WT,
    const float* __restrict__ bias1, const float* __restrict__ bias2,
    float* __restrict__ Cf, unsigned short* __restrict__ Cb, int ldc,
    int M, int Nreal, int K, int relu)
{
    constexpr int NF = NP / 32;
    constexpr int BCH = (NP * 4 + 255) / 256;
    const int t = threadIdx.x;
    const int row0 = bx * 64;
    const int w = t >> 6, l = t & 63;
    const int wr = w >> 1, wc = w & 1;
    const int lr = l & 15, q = l >> 4;
    const int ar = t >> 2, akq = t & 3;
    const int grow = row0 + ar;

    f32x4 acc[2][NF];
    #pragma unroll
    for (int m = 0; m < 2; ++m)
        #pragma unroll
        for (int n = 0; n < NF; ++n)
            acc[m][n] = (f32x4){0.f, 0.f, 0.f, 0.f};

    float afr[8];
    ushort8 ab0;
    ushort8 bb[BCH];

    auto loadTile = [&](int k0) {
        if (grow < M) {
            if (ABF) {
                ab0 = *(const ushort8*)(Ab + (size_t)grow * lda + k0 + akq * 8);
            } else {
                const float* p = Af + (size_t)grow * lda + k0 + akq * 8;
                ((float4*)afr)[0] = *(const float4*)p;
                ((float4*)afr)[1] = *(const float4*)(p + 4);
            }
        } else {
            if (ABF) {
                #pragma unroll
                for (int i = 0; i < 8; ++i) ab0[i] = 0;
            } else {
                #pragma unroll
                for (int i = 0; i < 8; ++i) afr[i] = 0.f;
            }
        }
        #pragma unroll
        for (int ch = 0; ch < BCH; ++ch) {
            int cid = t + ch * 256;
            if ((NP * 4) % 256 == 0 || cid < NP * 4) {
                int c = cid >> 2, kq = cid & 3;
                bb[ch] = *(const ushort8*)(WT + (size_t)c * K + k0 + kq * 8);
            }
        }
    };
    auto storeTile = [&](int buf) {
        ushort8 o;
        if (ABF) o = ab0;
        else {
            #pragma unroll
            for (int i = 0; i < 8; ++i) o[i] = f2bf(afr[i]);
        }
        *(ushort8*)(As + buf * 2560 + ar * 40 + akq * 8) = o;
        #pragma unroll
        for (int ch = 0; ch < BCH; ++ch) {
            int cid = t + ch * 256;
            if ((NP * 4) % 256 == 0 || cid < NP * 4) {
                int c = cid >> 2, kq = cid & 3;
                *(ushort8*)(Bs + buf * (NP * 40) + c * 40 + kq * 8) = bb[ch];
            }
        }
    };

    loadTile(0);
    storeTile(0);
    __syncthreads();
    const int nIter = K >> 5;
    for (int it = 0; it < nIter; ++it) {
        const int cur = it & 1;
        if (it + 1 < nIter) loadTile((it + 1) << 5);
        bf16x8 a[2], b[NF];
        #pragma unroll
        for (int m = 0; m < 2; ++m)
            a[m] = *(const bf16x8*)(As + cur * 2560 + (wr * 32 + m * 16 + lr) * 40 + q * 8);
        #pragma unroll
        for (int n = 0; n < NF; ++n)
            b[n] = *(const bf16x8*)(Bs + cur * (NP * 40) + (wc * (NP / 2) + n * 16 + lr) * 40 + q * 8);
        #pragma unroll
        for (int m = 0; m < 2; ++m)
            #pragma unroll
            for (int n = 0; n < NF; ++n)
                acc[m][n] = __builtin_amdgcn_mfma_f32_16x16x32_bf16(a[m], b[n], acc[m][n], 0, 0, 0);
        __syncthreads();
        if (it + 1 < nIter) storeTile(cur ^ 1);
        __syncthreads();
    }

    if constexpr (NORM) {
        // stash post-epilogue values in LDS (reuse As/Bs region), then
        // row-wise L2 normalize (64-wide rows) and write fp32.
        float* sm = (float*)As;  // 64 x 66 floats = 16896 B (fits 20480 B)
        #pragma unroll
        for (int m = 0; m < 2; ++m)
            #pragma unroll
            for (int j = 0; j < 4; ++j) {
                int rl = wr * 32 + m * 16 + q * 4 + j;
                #pragma unroll
                for (int n = 0; n < NF; ++n) {
                    int c = wc * (NP / 2) + n * 16 + lr;
                    float v = acc[m][n][j];
                    if (bias1) v += bias1[c];
                    if (bias2) v += bias2[c];
                    if (relu) v = fmaxf(v, 0.f);
                    sm[rl * 66 + c] = v;
                }
            }
        __syncthreads();
        for (int ri = 0; ri < 16; ++ri) {
            int rl = w * 16 + ri;
            int r = row0 + rl;
            float v = sm[rl * 66 + l];
            float s = v * v;
            #pragma unroll
            for (int off = 32; off; off >>= 1) s += __shfl_xor(s, off);
            float nrm = fmaxf(sqrtf(s), 1e-12f);
            if (r < M) Cf[(size_t)r * ldc + l] = v / nrm;
        }
        return;
    }

    #pragma unroll
    for (int m = 0; m < 2; ++m) {
        #pragma unroll
        for (int j = 0; j < 4; ++j) {
            int r = row0 + wr * 32 + m * 16 + q * 4 + j;
            if (r >= M) continue;
            #pragma unroll
            for (int n = 0; n < NF; ++n) {
                int c = wc * (NP / 2) + n * 16 + lr;
                float v = acc[m][n][j];
                if (c < Nreal) {
                    if (bias1) v += bias1[c];
                    if (bias2) v += bias2[c];
                    if (relu) v = fmaxf(v, 0.f);
                    if (Cf) Cf[(size_t)r * ldc + c] = v;
                } else {
                    v = 0.f;
                }
                if (Cb) Cb[(size_t)r * ldc + c] = f2bf(v);
            }
        }
    }
}

// ---------------------------------------------------------------------------
// emb_fill: blocks [0,GBU) user-embed GEMM, [GBU,GBU+GBR) repo-embed GEMM,
// rest CSR fill of both graphs (latency-bound; overlaps the GEMM blocks).
// ---------------------------------------------------------------------------
__global__ __launch_bounds__(256) void emb_fill(
    const float* __restrict__ user_feat, const float* __restrict__ repo_feat,
    const unsigned short* __restrict__ WTue, const unsigned short* __restrict__ WTre,
    const float* __restrict__ b_ue, const float* __restrict__ b_re,
    unsigned short* __restrict__ hUcat, unsigned short* __restrict__ hRcat,
    const int* __restrict__ us, const int* __restrict__ ud,
    const int* __restrict__ rs, const int* __restrict__ rd,
    int* __restrict__ cur_ur, int* __restrict__ csr_ur,
    int* __restrict__ cur_ru, int* __restrict__ csr_ru)
{
    __shared__ __align__(16) unsigned short SM[2 * 64 * 40 + 2 * 128 * 40];
    unsigned short* As = SM;
    unsigned short* Bs = SM + 2 * 64 * 40;
    int b = blockIdx.x;
    if (b < GBU) {
        gemm_body<128, false, false>(As, Bs, b, user_feat, nullptr, 256, WTue,
                                     b_ue, nullptr, nullptr, hUcat, 256,
                                     N_USER, D_EMB, D_IN, 0);
    } else if (b < GBU + GBR) {
        gemm_body<128, false, false>(As, Bs, b - GBU, repo_feat, nullptr, 256, WTre,
                                     b_re, nullptr, nullptr, hRcat, 256,
                                     N_REPO, D_EMB, D_IN, 0);
    } else {
        int e = (b - GBU - GBR) * 256 + threadIdx.x;
        if (e < NEDGE) {
            int p = atomicAdd(&cur_ur[ud[e]], 1);
            csr_ur[p] = us[e];
        } else if (e < 2 * NEDGE) {
            int i = e - NEDGE;
            int p = atomicAdd(&cur_ru[rd[i]], 1);
            csr_ru[p] = rs[i];
        }
    }
}

// ---------------------------------------------------------------------------
// segsum2: both directions in one dispatch. dst[node,coff:coff+D] =
// rs_d[node] * sum_e rs_s[csr[e]] * src[csr[e], 0:D]. bf16 in/out, fp32 acc.
// ---------------------------------------------------------------------------
__global__ __launch_bounds__(256) void segsum2(
    const unsigned short* __restrict__ srcU, const int* __restrict__ csrU,
    const int* __restrict__ offU, const float* __restrict__ rssU,
    const float* __restrict__ rsdU, unsigned short* __restrict__ dstU, int n_dstU,
    const unsigned short* __restrict__ srcR, const int* __restrict__ csrR,
    const int* __restrict__ offR, const float* __restrict__ rssR,
    const float* __restrict__ rsdR, unsigned short* __restrict__ dstR, int n_dstR,
    int lds_, int ldd, int coff, int d8, int nb, int blocksU)
{
    int b = blockIdx.x;
    const unsigned short* src; const int* csr; const int* off;
    const float* rss; const float* rsd; unsigned short* dst;
    int n_dst, nb0;
    if (b < blocksU) { src = srcU; csr = csrU; off = offU; rss = rssU; rsd = rsdU; dst = dstU; n_dst = n_dstU; nb0 = b; }
    else { src = srcR; csr = csrR; off = offR; rss = rssR; rsd = rsdR; dst = dstR; n_dst = n_dstR; nb0 = b - blocksU; }
    int ni = threadIdx.x / d8;
    int c8 = threadIdx.x - ni * d8;
    if (ni >= nb) return;
    int node = nb0 * nb + ni;
    if (node >= n_dst) return;
    int j0 = off[node], j1 = off[node + 1];
    float acc[8] = {};
    for (int j = j0; j < j1; ++j) {
        int s = csr[j];
        float sc = rss[s];
        ushort8 v = *(const ushort8*)(src + (size_t)s * lds_ + c8 * 8);
        #pragma unroll
        for (int i = 0; i < 8; ++i) acc[i] += bf2f(v[i]) * sc;
    }
    float sd = rsd[node];
    ushort8 o;
    #pragma unroll
    for (int i = 0; i < 8; ++i) o[i] = f2bf(acc[i] * sd);
    *(ushort8*)(dst + (size_t)node * ldd + coff + c8 * 8) = o;
}

// ---------------------------------------------------------------------------
// hid2 / out2: user+repo GEMMs of a layer in one dispatch.
// ---------------------------------------------------------------------------
__global__ __launch_bounds__(256) void hid2(
    const unsigned short* __restrict__ hUcat, const unsigned short* __restrict__ hRcat,
    const unsigned short* __restrict__ WTcat_u, const unsigned short* __restrict__ WTcat_r,
    const float* __restrict__ b_hcu, const float* __restrict__ b_hru,
    const float* __restrict__ b_hcr, const float* __restrict__ b_hur,
    unsigned short* __restrict__ Fcat, unsigned short* __restrict__ Gcat)
{
    __shared__ __align__(16) unsigned short SM[2 * 64 * 40 + 2 * 96 * 40];
    unsigned short* As = SM;
    unsigned short* Bs = SM + 2 * 64 * 40;
    int b = blockIdx.x;
    if (b < GBU)
        gemm_body<96, true, false>(As, Bs, b, nullptr, hUcat, 256, WTcat_u,
                                   b_hcu, b_hru, nullptr, Fcat, 192,
                                   N_USER, D_HID, 256, 1);
    else
        gemm_body<96, true, false>(As, Bs, b - GBU, nullptr, hRcat, 256, WTcat_r,
                                   b_hcr, b_hur, nullptr, Gcat, 192,
                                   N_REPO, D_HID, 256, 1);
}

__global__ __launch_bounds__(256) void out2(
    const unsigned short* __restrict__ Fcat, const unsigned short* __restrict__ Gcat,
    const unsigned short* __restrict__ WTo_u, const unsigned short* __restrict__ WTo_r,
    const float* __restrict__ b_ocu, const float* __restrict__ b_oru,
    const float* __restrict__ b_ocr, const float* __restrict__ b_our,
    float* __restrict__ hUn, float* __restrict__ hRn)
{
    __shared__ __align__(16) unsigned short SM[2 * 64 * 40 + 2 * 64 * 40];
    unsigned short* As = SM;
    unsigned short* Bs = SM + 2 * 64 * 40;
    int b = blockIdx.x;
    if (b < GBU)
        gemm_body<64, true, true>(As, Bs, b, nullptr, Fcat, 192, WTo_u,
                                  b_ocu, b_oru, hUn, nullptr, 64,
                                  N_USER, D_OUT, 192, 1);
    else
        gemm_body<64, true, true>(As, Bs, b - GBU, nullptr, Gcat, 192, WTo_r,
                                  b_ocr, b_our, hRn, nullptr, 64,
                                  N_REPO, D_OUT, 192, 1);
}

// ---------------------------------------------------------------------------
// Both score sets; 16 lanes per pair, float4 per lane.
// ---------------------------------------------------------------------------
__global__ void score_all(const float* __restrict__ nu, const float* __restrict__ nr,
                          const int* __restrict__ pu, const int* __restrict__ pr,
                          const int* __restrict__ qu, const int* __restrict__ qr,
                          float* __restrict__ out)
{
    int tid = blockIdx.x * 256 + threadIdx.x;
    int pair = tid >> 4, sl = tid & 15;
    if (pair >= 2 * NPAIR) return;
    int g = (pair < NPAIR) ? pair : pair - NPAIR;
    int iu = (pair < NPAIR) ? pu[g] : qu[g];
    int ir = (pair < NPAIR) ? pr[g] : qr[g];
    float4 a = *(const float4*)(nu + (size_t)iu * 64 + sl * 4);
    float4 b = *(const float4*)(nr + (size_t)ir * 64 + sl * 4);
    float s = a.x * b.x + a.y * b.y + a.z * b.z + a.w * b.w;
    s += __shfl_xor(s, 1);
    s += __shfl_xor(s, 2);
    s += __shfl_xor(s, 4);
    s += __shfl_xor(s, 8);
    if (sl == 0) out[pair] = s;
}

// ---------------------------------------------------------------------------
extern "C" void kernel_launch(void* const* d_in, const int* in_sizes, int n_in,
                              void* d_out, int out_size, void* d_ws, size_t ws_size,
                              hipStream_t stream)
{
    const float* user_feat = (const float*)d_in[0];
    const float* repo_feat = (const float*)d_in[1];
    const float* W_ue  = (const float*)d_in[2];   const float* b_ue  = (const float*)d_in[3];
    const float* W_re  = (const float*)d_in[4];   const float* b_re  = (const float*)d_in[5];
    const float* W_hur = (const float*)d_in[6];   const float* b_hur = (const float*)d_in[7];
    const float* W_hru = (const float*)d_in[8];   const float* b_hru = (const float*)d_in[9];
    const float* W_our = (const float*)d_in[10];  const float* b_our = (const float*)d_in[11];
    const float* W_oru = (const float*)d_in[12];  const float* b_oru = (const float*)d_in[13];
    const float* W_hcu = (const float*)d_in[14];  const float* b_hcu = (const float*)d_in[15];
    const float* W_hcr = (const float*)d_in[16];  const float* b_hcr = (const float*)d_in[17];
    const float* W_ocu = (const float*)d_in[18];  const float* b_ocu = (const float*)d_in[19];
    const float* W_ocr = (const float*)d_in[20];  const float* b_ocr = (const float*)d_in[21];
    const int* e_ur_src = (const int*)d_in[22];
    const int* e_ur_dst = (const int*)d_in[23];
    const int* e_ru_src = (const int*)d_in[24];
    const int* e_ru_dst = (const int*)d_in[25];
    const int* pos_u = (const int*)d_in[26];
    const int* pos_r = (const int*)d_in[27];
    const int* neg_u = (const int*)d_in[28];
    const int* neg_r = (const int*)d_in[29];

    char* base = (char*)d_ws;
    size_t cur = 0;
    auto alloc = [&](size_t bytes) {
        cur = (cur + 255) & ~(size_t)255;
        char* p = base + cur;
        cur += bytes;
        return p;
    };
    unsigned short* hUcat = (unsigned short*)alloc((size_t)N_USER * 256 * 2);
    unsigned short* hRcat = (unsigned short*)alloc((size_t)N_REPO * 256 * 2);
    unsigned short* Fcat  = (unsigned short*)alloc((size_t)N_USER * 192 * 2);
    unsigned short* Gcat  = (unsigned short*)alloc((size_t)N_REPO * 192 * 2);
    float* hUn = (float*)alloc((size_t)N_USER * 64 * 4);
    float* hRn = (float*)alloc((size_t)N_REPO * 64 * 4);
    float* RS  = (float*)alloc(300000 * 4);
    float* rs_ur_src = RS;
    float* rs_ur_dst = RS + N_USER;
    float* rs_ru_src = rs_ur_dst + N_REPO;
    float* rs_ru_dst = rs_ru_src + N_REPO;
    int* CNT = (int*)alloc(300000 * 4);
    int* cnt_ur_src = CNT;
    int* cnt_ur_dst = CNT + N_USER;
    int* cnt_ru_src = cnt_ur_dst + N_REPO;
    int* cnt_ru_dst = cnt_ru_src + N_REPO;
    int* off_ur = (int*)alloc((N_REPO + 1) * 4);
    int* off_ru = (int*)alloc((N_USER + 1) * 4);
    int* cur_ur = (int*)alloc(N_REPO * 4);
    int* cur_ru = (int*)alloc(N_USER * 4);
    int* bs_ur  = (int*)alloc(512 * 4);
    int* bs_ru  = (int*)alloc(512 * 4);
    int* csr_ur = (int*)alloc((size_t)NEDGE * 4);
    int* csr_ru = (int*)alloc((size_t)NEDGE * 4);
    unsigned short* WTarena = (unsigned short*)alloc(139264 * 2);
    unsigned short* WTue    = WTarena;
    unsigned short* WTre    = WTarena + 32768;
    unsigned short* WTcat_u = WTarena + 65536;
    unsigned short* WTcat_r = WTarena + 90112;
    unsigned short* WTo_u   = WTarena + 114688;
    unsigned short* WTo_r   = WTarena + 126976;

    // 1) zero counts
    hipMemsetAsync(CNT, 0, 300000 * sizeof(int), stream);
    // 2) weight convert + degree histograms (overlapped in one dispatch)
    prep<<<WCB + FILLB, 256, 0, stream>>>(
        W_ue, W_re, W_hcu, W_hru, W_hcr, W_hur, W_ocu, W_oru, W_ocr, W_our, WTarena,
        e_ur_src, e_ur_dst, e_ru_src, e_ru_dst,
        cnt_ur_src, cnt_ur_dst, cnt_ru_src, cnt_ru_dst);
    // 3) block scans + rsqrt (overlapped)
    scan_a<<<SCB + RSB, 256, 0, stream>>>(cnt_ur_dst, off_ur, bs_ur,
                                          cnt_ru_dst, off_ru, bs_ru, CNT, RS);
    scan_sums2<<<2, 512, 0, stream>>>(bs_ur, bs_ru);
    scan_fix_all<<<(N_REPO + N_USER + 2 + 255) / 256, 256, 0, stream>>>(
        off_ur, cur_ur, bs_ur, off_ru, cur_ru, bs_ru);
    // 4) embedding GEMMs + CSR fill (overlapped)
    emb_fill<<<GBU + GBR + FILLB, 256, 0, stream>>>(
        user_feat, repo_feat, WTue, WTre, b_ue, b_re, hUcat, hRcat,
        e_ur_src, e_ur_dst, e_ru_src, e_ru_dst,
        cur_ur, csr_ur, cur_ru, csr_ru);
    // 5) aggregate embeddings into cat cols [128:256]
    {
        int blocksU = (N_USER + 15) / 16, blocksR = (N_REPO + 15) / 16;
        segsum2<<<blocksU + blocksR, 256, 0, stream>>>(
            hRcat, csr_ru, off_ru, rs_ru_src, rs_ru_dst, hUcat, N_USER,
            hUcat, csr_ur, off_ur, rs_ur_src, rs_ur_dst, hRcat, N_REPO,
            256, 256, 128, 16, 16, blocksU);
    }
    // 6) hidden layer (fused residual+conv, both node types)
    hid2<<<GBU + GBR, 256, 0, stream>>>(hUcat, hRcat, WTcat_u, WTcat_r,
                                        b_hcu, b_hru, b_hcr, b_hur, Fcat, Gcat);
    // 7) aggregate hidden into cat cols [96:192]
    {
        int blocksU = (N_USER + 20) / 21, blocksR = (N_REPO + 20) / 21;
        segsum2<<<blocksU + blocksR, 256, 0, stream>>>(
            Gcat, csr_ru, off_ru, rs_ru_src, rs_ru_dst, Fcat, N_USER,
            Fcat, csr_ur, off_ur, rs_ur_src, rs_ur_dst, Gcat, N_REPO,
            192, 192, 96, 12, 21, blocksU);
    }
    // 8) output layer with fused row-normalize
    out2<<<GBU + GBR, 256, 0, stream>>>(Fcat, Gcat, WTo_u, WTo_r,
                                        b_ocu, b_oru, b_ocr, b_our, hUn, hRn);
    // 9) scores
    score_all<<<(2L * NPAIR * 16 + 255) / 256, 256, 0, stream>>>(
        hUn, hRn, pos_u, pos_r, neg_u, neg_r, (float*)d_out);
}

// Round 7
// 791.038 us; speedup vs baseline: 6.9376x; 1.0291x over previous
//
#include <hip/hip_runtime.h>
#include <hip/hip_bf16.h>

// Model sizes
#define N_USER 50000
#define N_REPO 100000
#define NEDGE  1000000
#define NPAIR  200000
#define D_IN   256
#define D_EMB  125
#define D_HID  96
#define D_OUT  64

// Block-partitioning constants
#define NBU 391     // ceil(N_REPO/256) scan blocks
#define NBR 196     // ceil(N_USER/256)
#define SCB (NBU + NBR)
#define RSB 1172    // ceil(300000/256)
#define WCB 544     // ceil(139264/256) weight-convert blocks
#define HFB 3907    // ceil(NEDGE/256): per-edge both-graph blocks
#define EGU 782     // user emb gemm blocks: ceil(50000/128)=391 rowblks x 2 col-halves
#define EGR 1564    // repo: 782 x 2
#define EGT (EGU + EGR)  // 2346

typedef short bf16x8 __attribute__((ext_vector_type(8)));
typedef float f32x4 __attribute__((ext_vector_type(4)));
typedef unsigned short ushort8 __attribute__((ext_vector_type(8)));

__device__ __forceinline__ unsigned short f2bf(float x) {
    union { float f; unsigned u; } c; c.f = x;
    unsigned r = c.u + 0x7fffu + ((c.u >> 16) & 1u);
    return (unsigned short)(r >> 16);
}
__device__ __forceinline__ float bf2f(unsigned short b) {
    union { unsigned u; float f; } c; c.u = ((unsigned)b) << 16;
    return c.f;
}

// ---------------------------------------------------------------------------
// histwc: blocks [0,WCB) convert/transpose/pad all 10 weights to bf16 arena;
// blocks [WCB,..): per-edge degree histograms for BOTH graphs (4 atomics/edge).
// Arena (shorts): WTue@0 [128][256] | WTre@32768 | WTcat_u@65536 [96][256]
// (W_hcu|W_hru) | WTcat_r@90112 | WTo_u@114688 [64][192] | WTo_r@126976.
// ---------------------------------------------------------------------------
__global__ __launch_bounds__(256) void histwc(
    const float* W0, const float* W1, const float* W2, const float* W3,
    const float* W4, const float* W5, const float* W6, const float* W7,
    const float* W8, const float* W9, unsigned short* __restrict__ arena,
    const int* __restrict__ us, const int* __restrict__ ud,
    const int* __restrict__ rs, const int* __restrict__ rd,
    int* __restrict__ c_ur_s, int* __restrict__ c_ur_d,
    int* __restrict__ c_ru_s, int* __restrict__ c_ru_d)
{
    int b = blockIdx.x;
    if (b < WCB) {
        int idx = b * 256 + threadIdx.x;
        if (idx >= 139264) return;
        const int cum[11]   = {0, 32768, 65536, 77824, 90112, 102400, 114688, 120832, 126976, 133120, 139264};
        const int dstoff[10]= {0, 32768, 65536, 65536, 90112, 90112, 114688, 114688, 126976, 126976};
        const int Kd[10]    = {256, 256, 256, 256, 256, 256, 192, 192, 192, 192};
        const int koff[10]  = {0, 0, 0, 128, 0, 128, 0, 96, 0, 96};
        const int Kdseg[10] = {256, 256, 128, 128, 128, 128, 96, 96, 96, 96};
        const int Ksrc[10]  = {256, 256, 125, 125, 125, 125, 96, 96, 96, 96};
        const int Nsrc[10]  = {125, 125, 96, 96, 96, 96, 64, 64, 64, 64};
        const float* Ws[10] = {W0, W1, W2, W3, W4, W5, W6, W7, W8, W9};
        int s = 0;
        #pragma unroll
        for (int i = 1; i < 10; ++i) if (idx >= cum[i]) s = i;
        int rem = idx - cum[s];
        int n = rem / Kdseg[s], k = rem - n * Kdseg[s];
        float v = (k < Ksrc[s] && n < Nsrc[s]) ? Ws[s][(size_t)k * Nsrc[s] + n] : 0.0f;
        arena[(size_t)dstoff[s] + (size_t)n * Kd[s] + koff[s] + k] = f2bf(v);
    } else {
        int e = (b - WCB) * 256 + threadIdx.x;
        if (e >= NEDGE) return;
        atomicAdd(&c_ur_s[us[e]], 1);
        atomicAdd(&c_ur_d[ud[e]], 1);
        atomicAdd(&c_ru_s[rs[e]], 1);
        atomicAdd(&c_ru_d[rd[e]], 1);
    }
}

// ---------------------------------------------------------------------------
// scan_a: [0,SCB) per-block exclusive scan of dst counts; [SCB,..) rsqrt-degs.
// ---------------------------------------------------------------------------
__global__ __launch_bounds__(256) void scan_a(
    const int* __restrict__ cnt_ur, int* __restrict__ off_ur, int* __restrict__ bs_ur,
    const int* __restrict__ cnt_ru, int* __restrict__ off_ru, int* __restrict__ bs_ru,
    const int* __restrict__ CNT, float* __restrict__ RS)
{
    int b = blockIdx.x;
    if (b < SCB) {
        __shared__ int s[256];
        const int* cnt; int* off; int* bs; int n, bi;
        if (b < NBU) { cnt = cnt_ur; off = off_ur; bs = bs_ur; n = N_REPO; bi = b; }
        else { cnt = cnt_ru; off = off_ru; bs = bs_ru; n = N_USER; bi = b - NBU; }
        int t = threadIdx.x, i = bi * 256 + t;
        int v = (i < n) ? cnt[i] : 0;
        s[t] = v;
        __syncthreads();
        for (int d = 1; d < 256; d <<= 1) {
            int u = (t >= d) ? s[t - d] : 0;
            __syncthreads();
            s[t] += u;
            __syncthreads();
        }
        if (i < n) off[i] = s[t] - v;
        if (t == 255) bs[bi] = s[255];
    } else {
        int i = (b - SCB) * 256 + threadIdx.x;
        if (i < 300000) RS[i] = rsqrtf((float)max(CNT[i], 1));
    }
}

__global__ void scan_sums2(int* __restrict__ bs_ur, int* __restrict__ bs_ru)
{
    __shared__ int s[512];
    int* b = (blockIdx.x == 0) ? bs_ur : bs_ru;
    int nb = (blockIdx.x == 0) ? NBU : NBR;
    int t = threadIdx.x;
    s[t] = (t < nb) ? b[t] : 0;
    __syncthreads();
    for (int d = 1; d < 512; d <<= 1) {
        int v = (t >= d) ? s[t - d] : 0;
        __syncthreads();
        s[t] += v;
        __syncthreads();
    }
    if (t < nb) b[t] = s[t];
}

__global__ void scan_fix_all(int* __restrict__ off_ur, int* __restrict__ cur_ur,
                             const int* __restrict__ bs_ur,
                             int* __restrict__ off_ru, int* __restrict__ cur_ru,
                             const int* __restrict__ bs_ru)
{
    int i = blockIdx.x * 256 + threadIdx.x;
    if (i <= N_REPO) {
        if (i == N_REPO) off_ur[i] = NEDGE;
        else {
            int blk = i >> 8;
            int v = off_ur[i] + (blk > 0 ? bs_ur[blk - 1] : 0);
            off_ur[i] = v;
            cur_ur[i] = v;
        }
    }
    int j = i - (N_REPO + 1);
    if (j >= 0 && j <= N_USER) {
        if (j == N_USER) off_ru[j] = NEDGE;
        else {
            int blk = j >> 8;
            int v = off_ru[j] + (blk > 0 ? bs_ru[blk - 1] : 0);
            off_ru[j] = v;
            cur_ru[j] = v;
        }
    }
}

// ---------------------------------------------------------------------------
// Barrier-free GEMM body. Whole B-panel (NPB cols x KK) staged once in LDS
// with XOR-swizzled 16B slots (2-way bank conflict = free), then each wave
// independently computes a 32-row strip: A-frags straight from global,
// B-frags from LDS, no __syncthreads in the K-loop.
// C layout per mfma_16x16x32: row=q*4+j (+m*16), col=n*16+lr.
// NORM: in-register row L2-normalize (NF*16 cols live in one q-group).
// ---------------------------------------------------------------------------
template<int NPB, int KK, bool ABF, bool NORM>
__device__ __forceinline__ void gemmw_body(
    unsigned short* __restrict__ Bs,   // NPB*256 shorts (rows padded to 32 slots)
    int rowblk, int col0,
    const float* __restrict__ Af, const unsigned short* __restrict__ Ab, int lda,
    const unsigned short* __restrict__ WT,  // [Ncols][KK] bf16
    const float* __restrict__ bias1, const float* __restrict__ bias2,
    float* __restrict__ Cf, unsigned short* __restrict__ Cb, int ldc,
    int M, int Nreal, int relu)
{
    constexpr int SLOTS = KK / 8;
    constexpr int NF = NPB / 16;
    constexpr int ITERS = KK / 32;
    const int t = threadIdx.x;

    // ---- stage B panel ----
    for (int sig = t; sig < NPB * SLOTS; sig += 256) {
        int cc = sig / SLOTS, s = sig - cc * SLOTS;
        ushort8 v = *(const ushort8*)(WT + (size_t)(col0 + cc) * KK + s * 8);
        *(ushort8*)(Bs + cc * 256 + ((s ^ (cc & 31)) << 3)) = v;
    }
    __syncthreads();

    const int wid = t >> 6, l = t & 63;
    const int lr = l & 15, q = l >> 4;
    const int wrow0 = rowblk * 128 + wid * 32;

    f32x4 acc[2][NF];
    #pragma unroll
    for (int m = 0; m < 2; ++m)
        #pragma unroll
        for (int n = 0; n < NF; ++n)
            acc[m][n] = (f32x4){0.f, 0.f, 0.f, 0.f};

    for (int it = 0; it < ITERS; ++it) {
        const int k0 = it * 32;
        bf16x8 a[2];
        #pragma unroll
        for (int m = 0; m < 2; ++m) {
            int row = wrow0 + m * 16 + lr;
            if (row < M) {
                if (ABF) {
                    a[m] = *(const bf16x8*)(Ab + (size_t)row * lda + k0 + q * 8);
                } else {
                    const float* p = Af + (size_t)row * lda + k0 + q * 8;
                    float4 u0 = *(const float4*)p;
                    float4 u1 = *(const float4*)(p + 4);
                    bf16x8 av;
                    av[0] = (short)f2bf(u0.x); av[1] = (short)f2bf(u0.y);
                    av[2] = (short)f2bf(u0.z); av[3] = (short)f2bf(u0.w);
                    av[4] = (short)f2bf(u1.x); av[5] = (short)f2bf(u1.y);
                    av[6] = (short)f2bf(u1.z); av[7] = (short)f2bf(u1.w);
                    a[m] = av;
                }
            } else {
                bf16x8 z = {0, 0, 0, 0, 0, 0, 0, 0};
                a[m] = z;
            }
        }
        bf16x8 bfr[NF];
        #pragma unroll
        for (int n = 0; n < NF; ++n) {
            int cc = n * 16 + lr;
            int s = it * 4 + q;
            bfr[n] = *(const bf16x8*)(Bs + cc * 256 + ((s ^ (cc & 31)) << 3));
        }
        #pragma unroll
        for (int m = 0; m < 2; ++m)
            #pragma unroll
            for (int n = 0; n < NF; ++n)
                acc[m][n] = __builtin_amdgcn_mfma_f32_16x16x32_bf16(a[m], bfr[n], acc[m][n], 0, 0, 0);
    }

    if constexpr (NORM) {
        // NPB==64, col0==0: one q-group's 16 lanes hold all 64 cols of a row.
        #pragma unroll
        for (int m = 0; m < 2; ++m) {
            #pragma unroll
            for (int j = 0; j < 4; ++j) {
                int r = wrow0 + m * 16 + q * 4 + j;
                float v[NF];
                float ss = 0.f;
                #pragma unroll
                for (int n = 0; n < NF; ++n) {
                    int c = n * 16 + lr;
                    float x = acc[m][n][j];
                    if (bias1) x += bias1[c];
                    if (bias2) x += bias2[c];
                    if (relu) x = fmaxf(x, 0.f);
                    v[n] = x;
                    ss += x * x;
                }
                ss += __shfl_xor(ss, 1);
                ss += __shfl_xor(ss, 2);
                ss += __shfl_xor(ss, 4);
                ss += __shfl_xor(ss, 8);
                float inv = 1.0f / fmaxf(sqrtf(ss), 1e-12f);
                if (r < M) {
                    #pragma unroll
                    for (int n = 0; n < NF; ++n)
                        Cf[(size_t)r * ldc + n * 16 + lr] = v[n] * inv;
                }
            }
        }
        return;
    }

    #pragma unroll
    for (int m = 0; m < 2; ++m) {
        #pragma unroll
        for (int j = 0; j < 4; ++j) {
            int r = wrow0 + m * 16 + q * 4 + j;
            if (r >= M) continue;
            #pragma unroll
            for (int n = 0; n < NF; ++n) {
                int c = col0 + n * 16 + lr;
                float x = acc[m][n][j];
                if (c < Nreal) {
                    if (bias1) x += bias1[c];
                    if (bias2) x += bias2[c];
                    if (relu) x = fmaxf(x, 0.f);
                    if (Cf) Cf[(size_t)r * ldc + c] = x;
                } else {
                    x = 0.f;
                }
                if (Cb) Cb[(size_t)r * ldc + c] = f2bf(x);
            }
        }
    }
}

// ---------------------------------------------------------------------------
// emb_fill2: [0,EGT) embedding GEMM blocks (fp32 A, 64-col halves);
// [EGT,..): CSR fill of both graphs per edge.
// ---------------------------------------------------------------------------
__global__ __launch_bounds__(256) void emb_fill2(
    const float* __restrict__ user_feat, const float* __restrict__ repo_feat,
    const unsigned short* __restrict__ WTue, const unsigned short* __restrict__ WTre,
    const float* __restrict__ b_ue, const float* __restrict__ b_re,
    unsigned short* __restrict__ hUcat, unsigned short* __restrict__ hRcat,
    const int* __restrict__ us, const int* __restrict__ ud,
    const int* __restrict__ rs, const int* __restrict__ rd,
    int* __restrict__ cur_ur, int* __restrict__ csr_ur,
    int* __restrict__ cur_ru, int* __restrict__ csr_ru)
{
    __shared__ __align__(16) unsigned short Bs[64 * 256];
    int b = blockIdx.x;
    if (b < EGU) {
        gemmw_body<64, 256, false, false>(Bs, b >> 1, (b & 1) * 64,
            user_feat, nullptr, 256, WTue, b_ue, nullptr,
            nullptr, hUcat, 256, N_USER, D_EMB, 0);
    } else if (b < EGT) {
        int b2 = b - EGU;
        gemmw_body<64, 256, false, false>(Bs, b2 >> 1, (b2 & 1) * 64,
            repo_feat, nullptr, 256, WTre, b_re, nullptr,
            nullptr, hRcat, 256, N_REPO, D_EMB, 0);
    } else {
        int e = (b - EGT) * 256 + threadIdx.x;
        if (e >= NEDGE) return;
        int p = atomicAdd(&cur_ur[ud[e]], 1);
        csr_ur[p] = us[e];
        int p2 = atomicAdd(&cur_ru[rd[e]], 1);
        csr_ru[p2] = rs[e];
    }
}

// ---------------------------------------------------------------------------
// hidg: hidden layer GEMMs (48-col halves), bf16 A = [h|agg] K=256.
// ---------------------------------------------------------------------------
__global__ __launch_bounds__(256) void hidg(
    const unsigned short* __restrict__ hUcat, const unsigned short* __restrict__ hRcat,
    const unsigned short* __restrict__ WTcat_u, const unsigned short* __restrict__ WTcat_r,
    const float* __restrict__ b_hcu, const float* __restrict__ b_hru,
    const float* __restrict__ b_hcr, const float* __restrict__ b_hur,
    unsigned short* __restrict__ Fcat, unsigned short* __restrict__ Gcat)
{
    __shared__ __align__(16) unsigned short Bs[48 * 256];
    int b = blockIdx.x;
    if (b < EGU) {
        gemmw_body<48, 256, true, false>(Bs, b >> 1, (b & 1) * 48,
            nullptr, hUcat, 256, WTcat_u, b_hcu, b_hru,
            nullptr, Fcat, 192, N_USER, D_HID, 1);
    } else {
        int b2 = b - EGU;
        gemmw_body<48, 256, true, false>(Bs, b2 >> 1, (b2 & 1) * 48,
            nullptr, hRcat, 256, WTcat_r, b_hcr, b_hur,
            nullptr, Gcat, 192, N_REPO, D_HID, 1);
    }
}

// ---------------------------------------------------------------------------
// outg: output GEMMs (full 64 cols) with fused in-register L2 row-normalize.
// ---------------------------------------------------------------------------
__global__ __launch_bounds__(256) void outg(
    const unsigned short* __restrict__ Fcat, const unsigned short* __restrict__ Gcat,
    const unsigned short* __restrict__ WTo_u, const unsigned short* __restrict__ WTo_r,
    const float* __restrict__ b_ocu, const float* __restrict__ b_oru,
    const float* __restrict__ b_ocr, const float* __restrict__ b_our,
    float* __restrict__ hUn, float* __restrict__ hRn)
{
    __shared__ __align__(16) unsigned short Bs[64 * 256];
    int b = blockIdx.x;
    if (b < 391) {
        gemmw_body<64, 192, true, true>(Bs, b, 0,
            nullptr, Fcat, 192, WTo_u, b_ocu, b_oru,
            hUn, nullptr, 64, N_USER, D_OUT, 1);
    } else {
        gemmw_body<64, 192, true, true>(Bs, b - 391, 0,
            nullptr, Gcat, 192, WTo_r, b_ocr, b_our,
            hRn, nullptr, 64, N_REPO, D_OUT, 1);
    }
}

// ---------------------------------------------------------------------------
// segsum2: both directions in one dispatch. dst[node,coff:coff+D] =
// rs_d[node] * sum_e rs_s[csr[e]] * src[csr[e], 0:D]. bf16 in/out, fp32 acc.
// ---------------------------------------------------------------------------
__global__ __launch_bounds__(256) void segsum2(
    const unsigned short* __restrict__ srcU, const int* __restrict__ csrU,
    const int* __restrict__ offU, const float* __restrict__ rssU,
    const float* __restrict__ rsdU, unsigned short* __restrict__ dstU, int n_dstU,
    const unsigned short* __restrict__ srcR, const int* __restrict__ csrR,
    const int* __restrict__ offR, const float* __restrict__ rssR,
    const float* __restrict__ rsdR, unsigned short* __restrict__ dstR, int n_dstR,
    int lds_, int ldd, int coff, int d8, int nb, int blocksU)
{
    int b = blockIdx.x;
    const unsigned short* src; const int* csr; const int* off;
    const float* rss; const float* rsd; unsigned short* dst;
    int n_dst, nb0;
    if (b < blocksU) { src = srcU; csr = csrU; off = offU; rss = rssU; rsd = rsdU; dst = dstU; n_dst = n_dstU; nb0 = b; }
    else { src = srcR; csr = csrR; off = offR; rss = rssR; rsd = rsdR; dst = dstR; n_dst = n_dstR; nb0 = b - blocksU; }
    int ni = threadIdx.x / d8;
    int c8 = threadIdx.x - ni * d8;
    if (ni >= nb) return;
    int node = nb0 * nb + ni;
    if (node >= n_dst) return;
    int j0 = off[node], j1 = off[node + 1];
    float acc[8] = {};
    for (int j = j0; j < j1; ++j) {
        int s = csr[j];
        float sc = rss[s];
        ushort8 v = *(const ushort8*)(src + (size_t)s * lds_ + c8 * 8);
        #pragma unroll
        for (int i = 0; i < 8; ++i) acc[i] += bf2f(v[i]) * sc;
    }
    float sd = rsd[node];
    ushort8 o;
    #pragma unroll
    for (int i = 0; i < 8; ++i) o[i] = f2bf(acc[i] * sd);
    *(ushort8*)(dst + (size_t)node * ldd + coff + c8 * 8) = o;
}

// ---------------------------------------------------------------------------
// Both score sets; 16 lanes per pair, float4 per lane.
// ---------------------------------------------------------------------------
__global__ void score_all(const float* __restrict__ nu, const float* __restrict__ nr,
                          const int* __restrict__ pu, const int* __restrict__ pr,
                          const int* __restrict__ qu, const int* __restrict__ qr,
                          float* __restrict__ out)
{
    int tid = blockIdx.x * 256 + threadIdx.x;
    int pair = tid >> 4, sl = tid & 15;
    if (pair >= 2 * NPAIR) return;
    int g = (pair < NPAIR) ? pair : pair - NPAIR;
    int iu = (pair < NPAIR) ? pu[g] : qu[g];
    int ir = (pair < NPAIR) ? pr[g] : qr[g];
    float4 a = *(const float4*)(nu + (size_t)iu * 64 + sl * 4);
    float4 b = *(const float4*)(nr + (size_t)ir * 64 + sl * 4);
    float s = a.x * b.x + a.y * b.y + a.z * b.z + a.w * b.w;
    s += __shfl_xor(s, 1);
    s += __shfl_xor(s, 2);
    s += __shfl_xor(s, 4);
    s += __shfl_xor(s, 8);
    if (sl == 0) out[pair] = s;
}

// ---------------------------------------------------------------------------
extern "C" void kernel_launch(void* const* d_in, const int* in_sizes, int n_in,
                              void* d_out, int out_size, void* d_ws, size_t ws_size,
                              hipStream_t stream)
{
    const float* user_feat = (const float*)d_in[0];
    const float* repo_feat = (const float*)d_in[1];
    const float* W_ue  = (const float*)d_in[2];   const float* b_ue  = (const float*)d_in[3];
    const float* W_re  = (const float*)d_in[4];   const float* b_re  = (const float*)d_in[5];
    const float* W_hur = (const float*)d_in[6];   const float* b_hur = (const float*)d_in[7];
    const float* W_hru = (const float*)d_in[8];   const float* b_hru = (const float*)d_in[9];
    const float* W_our = (const float*)d_in[10];  const float* b_our = (const float*)d_in[11];
    const float* W_oru = (const float*)d_in[12];  const float* b_oru = (const float*)d_in[13];
    const float* W_hcu = (const float*)d_in[14];  const float* b_hcu = (const float*)d_in[15];
    const float* W_hcr = (const float*)d_in[16];  const float* b_hcr = (const float*)d_in[17];
    const float* W_ocu = (const float*)d_in[18];  const float* b_ocu = (const float*)d_in[19];
    const float* W_ocr = (const float*)d_in[20];  const float* b_ocr = (const float*)d_in[21];
    const int* e_ur_src = (const int*)d_in[22];
    const int* e_ur_dst = (const int*)d_in[23];
    const int* e_ru_src = (const int*)d_in[24];
    const int* e_ru_dst = (const int*)d_in[25];
    const int* pos_u = (const int*)d_in[26];
    const int* pos_r = (const int*)d_in[27];
    const int* neg_u = (const int*)d_in[28];
    const int* neg_r = (const int*)d_in[29];

    char* base = (char*)d_ws;
    size_t cur = 0;
    auto alloc = [&](size_t bytes) {
        cur = (cur + 255) & ~(size_t)255;
        char* p = base + cur;
        cur += bytes;
        return p;
    };
    unsigned short* hUcat = (unsigned short*)alloc((size_t)N_USER * 256 * 2);
    unsigned short* hRcat = (unsigned short*)alloc((size_t)N_REPO * 256 * 2);
    unsigned short* Fcat  = (unsigned short*)alloc((size_t)N_USER * 192 * 2);
    unsigned short* Gcat  = (unsigned short*)alloc((size_t)N_REPO * 192 * 2);
    float* hUn = (float*)alloc((size_t)N_USER * 64 * 4);
    float* hRn = (float*)alloc((size_t)N_REPO * 64 * 4);
    float* RS  = (float*)alloc(300000 * 4);
    float* rs_ur_src = RS;
    float* rs_ur_dst = RS + N_USER;
    float* rs_ru_src = rs_ur_dst + N_REPO;
    float* rs_ru_dst = rs_ru_src + N_REPO;
    int* CNT = (int*)alloc(300000 * 4);
    int* cnt_ur_src = CNT;
    int* cnt_ur_dst = CNT + N_USER;
    int* cnt_ru_src = cnt_ur_dst + N_REPO;
    int* cnt_ru_dst = cnt_ru_src + N_REPO;
    int* off_ur = (int*)alloc((N_REPO + 1) * 4);
    int* off_ru = (int*)alloc((N_USER + 1) * 4);
    int* cur_ur = (int*)alloc(N_REPO * 4);
    int* cur_ru = (int*)alloc(N_USER * 4);
    int* bs_ur  = (int*)alloc(512 * 4);
    int* bs_ru  = (int*)alloc(512 * 4);
    int* csr_ur = (int*)alloc((size_t)NEDGE * 4);
    int* csr_ru = (int*)alloc((size_t)NEDGE * 4);
    unsigned short* WTarena = (unsigned short*)alloc(139264 * 2);
    unsigned short* WTue    = WTarena;
    unsigned short* WTre    = WTarena + 32768;
    unsigned short* WTcat_u = WTarena + 65536;
    unsigned short* WTcat_r = WTarena + 90112;
    unsigned short* WTo_u   = WTarena + 114688;
    unsigned short* WTo_r   = WTarena + 126976;

    // 1) zero counts
    hipMemsetAsync(CNT, 0, 300000 * sizeof(int), stream);
    // 2) weight convert + degree histograms
    histwc<<<WCB + HFB, 256, 0, stream>>>(
        W_ue, W_re, W_hcu, W_hru, W_hcr, W_hur, W_ocu, W_oru, W_ocr, W_our, WTarena,
        e_ur_src, e_ur_dst, e_ru_src, e_ru_dst,
        cnt_ur_src, cnt_ur_dst, cnt_ru_src, cnt_ru_dst);
    // 3) block scans + rsqrt
    scan_a<<<SCB + RSB, 256, 0, stream>>>(cnt_ur_dst, off_ur, bs_ur,
                                          cnt_ru_dst, off_ru, bs_ru, CNT, RS);
    scan_sums2<<<2, 512, 0, stream>>>(bs_ur, bs_ru);
    scan_fix_all<<<(N_REPO + N_USER + 2 + 255) / 256, 256, 0, stream>>>(
        off_ur, cur_ur, bs_ur, off_ru, cur_ru, bs_ru);
    // 4) embedding GEMMs + CSR fill (overlapped)
    emb_fill2<<<EGT + HFB, 256, 0, stream>>>(
        user_feat, repo_feat, WTue, WTre, b_ue, b_re, hUcat, hRcat,
        e_ur_src, e_ur_dst, e_ru_src, e_ru_dst,
        cur_ur, csr_ur, cur_ru, csr_ru);
    // 5) aggregate embeddings into cat cols [128:256]
    {
        int blocksU = (N_USER + 15) / 16, blocksR = (N_REPO + 15) / 16;
        segsum2<<<blocksU + blocksR, 256, 0, stream>>>(
            hRcat, csr_ru, off_ru, rs_ru_src, rs_ru_dst, hUcat, N_USER,
            hUcat, csr_ur, off_ur, rs_ur_src, rs_ur_dst, hRcat, N_REPO,
            256, 256, 128, 16, 16, blocksU);
    }
    // 6) hidden layer
    hidg<<<EGT, 256, 0, stream>>>(hUcat, hRcat, WTcat_u, WTcat_r,
                                  b_hcu, b_hru, b_hcr, b_hur, Fcat, Gcat);
    // 7) aggregate hidden into cat cols [96:192]
    {
        int blocksU = (N_USER + 20) / 21, blocksR = (N_REPO + 20) / 21;
        segsum2<<<blocksU + blocksR, 256, 0, stream>>>(
            Gcat, csr_ru, off_ru, rs_ru_src, rs_ru_dst, Fcat, N_USER,
            Fcat, csr_ur, off_ur, rs_ur_src, rs_ur_dst, Gcat, N_REPO,
            192, 192, 96, 12, 21, blocksU);
    }
    // 8) output layer with fused in-register normalize
    outg<<<391 + 782, 256, 0, stream>>>(Fcat, Gcat, WTo_u, WTo_r,
                                        b_ocu, b_oru, b_ocr, b_our, hUn, hRn);
    // 9) scores
    score_all<<<(2L * NPAIR * 16 + 255) / 256, 256, 0, stream>>>(
        hUn, hRn, pos_u, pos_r, neg_u, neg_r, (float*)d_out);
}

// Round 8
// 740.974 us; speedup vs baseline: 7.4063x; 1.0676x over previous
//
#include <hip/hip_runtime.h>
#include <hip/hip_bf16.h>

// Model sizes
#define N_USER 50000
#define N_REPO 100000
#define NEDGE  1000000
#define NPAIR  200000
#define D_IN   256
#define D_EMB  125
#define D_HID  96
#define D_OUT  64

// Block-partitioning constants
#define WCB 544     // ceil(139264/256) weight-convert blocks
#define INITB 1172  // ceil(300000/256) head/count init blocks
#define HFB 3907    // ceil(NEDGE/256) per-edge blocks (both graphs per thread)
#define EGU 782     // user emb gemm blocks: 391 rowblks x 2 col-halves
#define EGR 1564    // repo: 782 x 2
#define EGT (EGU + EGR)  // 2346

typedef short bf16x8 __attribute__((ext_vector_type(8)));
typedef float f32x4 __attribute__((ext_vector_type(4)));
typedef unsigned short ushort8 __attribute__((ext_vector_type(8)));

__device__ __forceinline__ unsigned short f2bf(float x) {
    union { float f; unsigned u; } c; c.f = x;
    unsigned r = c.u + 0x7fffu + ((c.u >> 16) & 1u);
    return (unsigned short)(r >> 16);
}
__device__ __forceinline__ float bf2f(unsigned short b) {
    union { unsigned u; float f; } c; c.u = ((unsigned)b) << 16;
    return c.f;
}

// ---------------------------------------------------------------------------
// init_wc: [0,WCB) convert/transpose/pad all 10 weights to bf16 arena;
// [WCB,..): init heads (-1) and src-degree counters (0).
// INITA layout (ints): head_ur[100000] | head_ru[50000] | cnt_ur_s[50000]
// | cnt_ru_s[100000]  (first 150000 -> -1, rest -> 0)
// Arena (shorts): WTue@0 [128][256] | WTre@32768 | WTcat_u@65536 [96][256]
// (W_hcu|W_hru) | WTcat_r@90112 | WTo_u@114688 [64][192] | WTo_r@126976.
// ---------------------------------------------------------------------------
__global__ __launch_bounds__(256) void init_wc(
    const float* W0, const float* W1, const float* W2, const float* W3,
    const float* W4, const float* W5, const float* W6, const float* W7,
    const float* W8, const float* W9, unsigned short* __restrict__ arena,
    int* __restrict__ INITA)
{
    int b = blockIdx.x;
    if (b < WCB) {
        int idx = b * 256 + threadIdx.x;
        if (idx >= 139264) return;
        const int cum[11]   = {0, 32768, 65536, 77824, 90112, 102400, 114688, 120832, 126976, 133120, 139264};
        const int dstoff[10]= {0, 32768, 65536, 65536, 90112, 90112, 114688, 114688, 126976, 126976};
        const int Kd[10]    = {256, 256, 256, 256, 256, 256, 192, 192, 192, 192};
        const int koff[10]  = {0, 0, 0, 128, 0, 128, 0, 96, 0, 96};
        const int Kdseg[10] = {256, 256, 128, 128, 128, 128, 96, 96, 96, 96};
        const int Ksrc[10]  = {256, 256, 125, 125, 125, 125, 96, 96, 96, 96};
        const int Nsrc[10]  = {125, 125, 96, 96, 96, 96, 64, 64, 64, 64};
        const float* Ws[10] = {W0, W1, W2, W3, W4, W5, W6, W7, W8, W9};
        int s = 0;
        #pragma unroll
        for (int i = 1; i < 10; ++i) if (idx >= cum[i]) s = i;
        int rem = idx - cum[s];
        int n = rem / Kdseg[s], k = rem - n * Kdseg[s];
        float v = (k < Ksrc[s] && n < Nsrc[s]) ? Ws[s][(size_t)k * Nsrc[s] + n] : 0.0f;
        arena[(size_t)dstoff[s] + (size_t)n * Kd[s] + koff[s] + k] = f2bf(v);
    } else {
        int i = (b - WCB) * 256 + threadIdx.x;
        if (i < 300000) INITA[i] = (i < 150000) ? -1 : 0;
    }
}

// ---------------------------------------------------------------------------
// Barrier-free GEMM body (unchanged from r7). Whole B-panel in LDS once,
// each wave owns a 32-row strip, A-frags from global, no sync in K-loop.
// ---------------------------------------------------------------------------
template<int NPB, int KK, bool ABF, bool NORM>
__device__ __forceinline__ void gemmw_body(
    unsigned short* __restrict__ Bs,
    int rowblk, int col0,
    const float* __restrict__ Af, const unsigned short* __restrict__ Ab, int lda,
    const unsigned short* __restrict__ WT,
    const float* __restrict__ bias1, const float* __restrict__ bias2,
    float* __restrict__ Cf, unsigned short* __restrict__ Cb, int ldc,
    int M, int Nreal, int relu)
{
    constexpr int SLOTS = KK / 8;
    constexpr int NF = NPB / 16;
    constexpr int ITERS = KK / 32;
    const int t = threadIdx.x;

    for (int sig = t; sig < NPB * SLOTS; sig += 256) {
        int cc = sig / SLOTS, s = sig - cc * SLOTS;
        ushort8 v = *(const ushort8*)(WT + (size_t)(col0 + cc) * KK + s * 8);
        *(ushort8*)(Bs + cc * 256 + ((s ^ (cc & 31)) << 3)) = v;
    }
    __syncthreads();

    const int wid = t >> 6, l = t & 63;
    const int lr = l & 15, q = l >> 4;
    const int wrow0 = rowblk * 128 + wid * 32;

    f32x4 acc[2][NF];
    #pragma unroll
    for (int m = 0; m < 2; ++m)
        #pragma unroll
        for (int n = 0; n < NF; ++n)
            acc[m][n] = (f32x4){0.f, 0.f, 0.f, 0.f};

    for (int it = 0; it < ITERS; ++it) {
        const int k0 = it * 32;
        bf16x8 a[2];
        #pragma unroll
        for (int m = 0; m < 2; ++m) {
            int row = wrow0 + m * 16 + lr;
            if (row < M) {
                if (ABF) {
                    a[m] = *(const bf16x8*)(Ab + (size_t)row * lda + k0 + q * 8);
                } else {
                    const float* p = Af + (size_t)row * lda + k0 + q * 8;
                    float4 u0 = *(const float4*)p;
                    float4 u1 = *(const float4*)(p + 4);
                    bf16x8 av;
                    av[0] = (short)f2bf(u0.x); av[1] = (short)f2bf(u0.y);
                    av[2] = (short)f2bf(u0.z); av[3] = (short)f2bf(u0.w);
                    av[4] = (short)f2bf(u1.x); av[5] = (short)f2bf(u1.y);
                    av[6] = (short)f2bf(u1.z); av[7] = (short)f2bf(u1.w);
                    a[m] = av;
                }
            } else {
                bf16x8 z = {0, 0, 0, 0, 0, 0, 0, 0};
                a[m] = z;
            }
        }
        bf16x8 bfr[NF];
        #pragma unroll
        for (int n = 0; n < NF; ++n) {
            int cc = n * 16 + lr;
            int s = it * 4 + q;
            bfr[n] = *(const bf16x8*)(Bs + cc * 256 + ((s ^ (cc & 31)) << 3));
        }
        #pragma unroll
        for (int m = 0; m < 2; ++m)
            #pragma unroll
            for (int n = 0; n < NF; ++n)
                acc[m][n] = __builtin_amdgcn_mfma_f32_16x16x32_bf16(a[m], bfr[n], acc[m][n], 0, 0, 0);
    }

    if constexpr (NORM) {
        #pragma unroll
        for (int m = 0; m < 2; ++m) {
            #pragma unroll
            for (int j = 0; j < 4; ++j) {
                int r = wrow0 + m * 16 + q * 4 + j;
                float v[NF];
                float ss = 0.f;
                #pragma unroll
                for (int n = 0; n < NF; ++n) {
                    int c = n * 16 + lr;
                    float x = acc[m][n][j];
                    if (bias1) x += bias1[c];
                    if (bias2) x += bias2[c];
                    if (relu) x = fmaxf(x, 0.f);
                    v[n] = x;
                    ss += x * x;
                }
                ss += __shfl_xor(ss, 1);
                ss += __shfl_xor(ss, 2);
                ss += __shfl_xor(ss, 4);
                ss += __shfl_xor(ss, 8);
                float inv = 1.0f / fmaxf(sqrtf(ss), 1e-12f);
                if (r < M) {
                    #pragma unroll
                    for (int n = 0; n < NF; ++n)
                        Cf[(size_t)r * ldc + n * 16 + lr] = v[n] * inv;
                }
            }
        }
        return;
    }

    #pragma unroll
    for (int m = 0; m < 2; ++m) {
        #pragma unroll
        for (int j = 0; j < 4; ++j) {
            int r = wrow0 + m * 16 + q * 4 + j;
            if (r >= M) continue;
            #pragma unroll
            for (int n = 0; n < NF; ++n) {
                int c = col0 + n * 16 + lr;
                float x = acc[m][n][j];
                if (c < Nreal) {
                    if (bias1) x += bias1[c];
                    if (bias2) x += bias2[c];
                    if (relu) x = fmaxf(x, 0.f);
                    if (Cf) Cf[(size_t)r * ldc + c] = x;
                } else {
                    x = 0.f;
                }
                if (Cb) Cb[(size_t)r * ldc + c] = f2bf(x);
            }
        }
    }
}

// ---------------------------------------------------------------------------
// build_emb: [0,EGT) embedding GEMM blocks; [EGT,..): per edge, push onto
// both graphs' dst-linked-lists (atomicExch head + 8B record) and count
// src out-degrees. 6 random line-ops per edge total.
// ---------------------------------------------------------------------------
__global__ __launch_bounds__(256) void build_emb(
    const float* __restrict__ user_feat, const float* __restrict__ repo_feat,
    const unsigned short* __restrict__ WTue, const unsigned short* __restrict__ WTre,
    const float* __restrict__ b_ue, const float* __restrict__ b_re,
    unsigned short* __restrict__ hUcat, unsigned short* __restrict__ hRcat,
    const int* __restrict__ us, const int* __restrict__ ud,
    const int* __restrict__ rs, const int* __restrict__ rd,
    int* __restrict__ head_ur, int2* __restrict__ rec_ur,
    int* __restrict__ head_ru, int2* __restrict__ rec_ru,
    int* __restrict__ cnt_ur_s, int* __restrict__ cnt_ru_s)
{
    __shared__ __align__(16) unsigned short Bs[64 * 256];
    int b = blockIdx.x;
    if (b < EGU) {
        gemmw_body<64, 256, false, false>(Bs, b >> 1, (b & 1) * 64,
            user_feat, nullptr, 256, WTue, b_ue, nullptr,
            nullptr, hUcat, 256, N_USER, D_EMB, 0);
    } else if (b < EGT) {
        int b2 = b - EGU;
        gemmw_body<64, 256, false, false>(Bs, b2 >> 1, (b2 & 1) * 64,
            repo_feat, nullptr, 256, WTre, b_re, nullptr,
            nullptr, hRcat, 256, N_REPO, D_EMB, 0);
    } else {
        int e = (b - EGT) * 256 + threadIdx.x;
        if (e >= NEDGE) return;
        // ur edge: user -> repo (dst = repo)
        int u = us[e], r = ud[e];
        int old = atomicExch(&head_ur[r], e);
        rec_ur[e] = make_int2(u, old);
        atomicAdd(&cnt_ur_s[u], 1);
        // ru edge: repo -> user (dst = user)
        int rr = rs[e], uu = rd[e];
        int old2 = atomicExch(&head_ru[uu], e);
        rec_ru[e] = make_int2(rr, old2);
        atomicAdd(&cnt_ru_s[rr], 1);
    }
}

// ---------------------------------------------------------------------------
// segsum_list: pull aggregation by walking dst linked lists; both directions
// in one dispatch. dst[node, coff:coff+D] = rsqrt(max(deg_in,1)) *
// sum_e rsqrt(max(cnt_s[src],1)) * src[srcnode, 0:D]. bf16 in/out, fp32 acc.
// Thread group = (node, 8-col chunk); all chunks walk the same chain
// (rec loads broadcast within the group).
// ---------------------------------------------------------------------------
__global__ __launch_bounds__(256) void segsum_list(
    const unsigned short* __restrict__ srcU, const int* __restrict__ headU,
    const int2* __restrict__ recU, const int* __restrict__ cntU,
    unsigned short* __restrict__ dstU, int n_dstU,
    const unsigned short* __restrict__ srcR, const int* __restrict__ headR,
    const int2* __restrict__ recR, const int* __restrict__ cntR,
    unsigned short* __restrict__ dstR, int n_dstR,
    int lds_, int ldd, int coff, int d8, int nb, int blocksU)
{
    int b = blockIdx.x;
    const unsigned short* src; const int* head; const int2* rec; const int* cnt;
    unsigned short* dst;
    int n_dst, nb0;
    if (b < blocksU) { src = srcU; head = headU; rec = recU; cnt = cntU; dst = dstU; n_dst = n_dstU; nb0 = b; }
    else { src = srcR; head = headR; rec = recR; cnt = cntR; dst = dstR; n_dst = n_dstR; nb0 = b - blocksU; }
    int ni = threadIdx.x / d8;
    int c8 = threadIdx.x - ni * d8;
    if (ni >= nb) return;
    int node = nb0 * nb + ni;
    if (node >= n_dst) return;
    float acc[8] = {};
    int e = head[node];
    int n = 0;
    while (e >= 0) {
        int2 rc = rec[e];
        int s = rc.x;
        float sc = rsqrtf((float)max(cnt[s], 1));
        ushort8 v = *(const ushort8*)(src + (size_t)s * lds_ + c8 * 8);
        #pragma unroll
        for (int i = 0; i < 8; ++i) acc[i] += bf2f(v[i]) * sc;
        ++n;
        e = rc.y;
    }
    float sd = rsqrtf((float)max(n, 1));
    ushort8 o;
    #pragma unroll
    for (int i = 0; i < 8; ++i) o[i] = f2bf(acc[i] * sd);
    *(ushort8*)(dst + (size_t)node * ldd + coff + c8 * 8) = o;
}

// ---------------------------------------------------------------------------
// hidg: hidden layer GEMMs (48-col halves), bf16 A = [h|agg] K=256.
// ---------------------------------------------------------------------------
__global__ __launch_bounds__(256) void hidg(
    const unsigned short* __restrict__ hUcat, const unsigned short* __restrict__ hRcat,
    const unsigned short* __restrict__ WTcat_u, const unsigned short* __restrict__ WTcat_r,
    const float* __restrict__ b_hcu, const float* __restrict__ b_hru,
    const float* __restrict__ b_hcr, const float* __restrict__ b_hur,
    unsigned short* __restrict__ Fcat, unsigned short* __restrict__ Gcat)
{
    __shared__ __align__(16) unsigned short Bs[48 * 256];
    int b = blockIdx.x;
    if (b < EGU) {
        gemmw_body<48, 256, true, false>(Bs, b >> 1, (b & 1) * 48,
            nullptr, hUcat, 256, WTcat_u, b_hcu, b_hru,
            nullptr, Fcat, 192, N_USER, D_HID, 1);
    } else {
        int b2 = b - EGU;
        gemmw_body<48, 256, true, false>(Bs, b2 >> 1, (b2 & 1) * 48,
            nullptr, hRcat, 256, WTcat_r, b_hcr, b_hur,
            nullptr, Gcat, 192, N_REPO, D_HID, 1);
    }
}

// ---------------------------------------------------------------------------
// outg: output GEMMs (full 64 cols) with fused in-register L2 row-normalize.
// ---------------------------------------------------------------------------
__global__ __launch_bounds__(256) void outg(
    const unsigned short* __restrict__ Fcat, const unsigned short* __restrict__ Gcat,
    const unsigned short* __restrict__ WTo_u, const unsigned short* __restrict__ WTo_r,
    const float* __restrict__ b_ocu, const float* __restrict__ b_oru,
    const float* __restrict__ b_ocr, const float* __restrict__ b_our,
    float* __restrict__ hUn, float* __restrict__ hRn)
{
    __shared__ __align__(16) unsigned short Bs[64 * 256];
    int b = blockIdx.x;
    if (b < 391) {
        gemmw_body<64, 192, true, true>(Bs, b, 0,
            nullptr, Fcat, 192, WTo_u, b_ocu, b_oru,
            hUn, nullptr, 64, N_USER, D_OUT, 1);
    } else {
        gemmw_body<64, 192, true, true>(Bs, b - 391, 0,
            nullptr, Gcat, 192, WTo_r, b_ocr, b_our,
            hRn, nullptr, 64, N_REPO, D_OUT, 1);
    }
}

// ---------------------------------------------------------------------------
// Both score sets; 16 lanes per pair, float4 per lane.
// ---------------------------------------------------------------------------
__global__ void score_all(const float* __restrict__ nu, const float* __restrict__ nr,
                          const int* __restrict__ pu, const int* __restrict__ pr,
                          const int* __restrict__ qu, const int* __restrict__ qr,
                          float* __restrict__ out)
{
    int tid = blockIdx.x * 256 + threadIdx.x;
    int pair = tid >> 4, sl = tid & 15;
    if (pair >= 2 * NPAIR) return;
    int g = (pair < NPAIR) ? pair : pair - NPAIR;
    int iu = (pair < NPAIR) ? pu[g] : qu[g];
    int ir = (pair < NPAIR) ? pr[g] : qr[g];
    float4 a = *(const float4*)(nu + (size_t)iu * 64 + sl * 4);
    float4 b = *(const float4*)(nr + (size_t)ir * 64 + sl * 4);
    float s = a.x * b.x + a.y * b.y + a.z * b.z + a.w * b.w;
    s += __shfl_xor(s, 1);
    s += __shfl_xor(s, 2);
    s += __shfl_xor(s, 4);
    s += __shfl_xor(s, 8);
    if (sl == 0) out[pair] = s;
}

// ---------------------------------------------------------------------------
extern "C" void kernel_launch(void* const* d_in, const int* in_sizes, int n_in,
                              void* d_out, int out_size, void* d_ws, size_t ws_size,
                              hipStream_t stream)
{
    const float* user_feat = (const float*)d_in[0];
    const float* repo_feat = (const float*)d_in[1];
    const float* W_ue  = (const float*)d_in[2];   const float* b_ue  = (const float*)d_in[3];
    const float* W_re  = (const float*)d_in[4];   const float* b_re  = (const float*)d_in[5];
    const float* W_hur = (const float*)d_in[6];   const float* b_hur = (const float*)d_in[7];
    const float* W_hru = (const float*)d_in[8];   const float* b_hru = (const float*)d_in[9];
    const float* W_our = (const float*)d_in[10];  const float* b_our = (const float*)d_in[11];
    const float* W_oru = (const float*)d_in[12];  const float* b_oru = (const float*)d_in[13];
    const float* W_hcu = (const float*)d_in[14];  const float* b_hcu = (const float*)d_in[15];
    const float* W_hcr = (const float*)d_in[16];  const float* b_hcr = (const float*)d_in[17];
    const float* W_ocu = (const float*)d_in[18];  const float* b_ocu = (const float*)d_in[19];
    const float* W_ocr = (const float*)d_in[20];  const float* b_ocr = (const float*)d_in[21];
    const int* e_ur_src = (const int*)d_in[22];
    const int* e_ur_dst = (const int*)d_in[23];
    const int* e_ru_src = (const int*)d_in[24];
    const int* e_ru_dst = (const int*)d_in[25];
    const int* pos_u = (const int*)d_in[26];
    const int* pos_r = (const int*)d_in[27];
    const int* neg_u = (const int*)d_in[28];
    const int* neg_r = (const int*)d_in[29];

    char* base = (char*)d_ws;
    size_t cur = 0;
    auto alloc = [&](size_t bytes) {
        cur = (cur + 255) & ~(size_t)255;
        char* p = base + cur;
        cur += bytes;
        return p;
    };
    unsigned short* hUcat = (unsigned short*)alloc((size_t)N_USER * 256 * 2);
    unsigned short* hRcat = (unsigned short*)alloc((size_t)N_REPO * 256 * 2);
    unsigned short* Fcat  = (unsigned short*)alloc((size_t)N_USER * 192 * 2);
    unsigned short* Gcat  = (unsigned short*)alloc((size_t)N_REPO * 192 * 2);
    float* hUn = (float*)alloc((size_t)N_USER * 64 * 4);
    float* hRn = (float*)alloc((size_t)N_REPO * 64 * 4);
    int* INITA = (int*)alloc(300000 * 4);
    int* head_ur  = INITA;             // [N_REPO]  list heads of ur graph (dst=repo)
    int* head_ru  = INITA + 100000;    // [N_USER]  list heads of ru graph (dst=user)
    int* cnt_ur_s = INITA + 150000;    // [N_USER]  user out-deg in ur
    int* cnt_ru_s = INITA + 200000;    // [N_REPO]  repo out-deg in ru
    int2* rec_ur = (int2*)alloc((size_t)NEDGE * 8);
    int2* rec_ru = (int2*)alloc((size_t)NEDGE * 8);
    unsigned short* WTarena = (unsigned short*)alloc(139264 * 2);
    unsigned short* WTue    = WTarena;
    unsigned short* WTre    = WTarena + 32768;
    unsigned short* WTcat_u = WTarena + 65536;
    unsigned short* WTcat_r = WTarena + 90112;
    unsigned short* WTo_u   = WTarena + 114688;
    unsigned short* WTo_r   = WTarena + 126976;

    // 1) weight convert + head/count init (one dispatch, no memset needed)
    init_wc<<<WCB + INITB, 256, 0, stream>>>(
        W_ue, W_re, W_hcu, W_hru, W_hcr, W_hur, W_ocu, W_oru, W_ocr, W_our,
        WTarena, INITA);
    // 2) embedding GEMMs + linked-list build + src-degree hist (overlapped)
    build_emb<<<EGT + HFB, 256, 0, stream>>>(
        user_feat, repo_feat, WTue, WTre, b_ue, b_re, hUcat, hRcat,
        e_ur_src, e_ur_dst, e_ru_src, e_ru_dst,
        head_ur, rec_ur, head_ru, rec_ru, cnt_ur_s, cnt_ru_s);
    // 3) aggregate embeddings into cat cols [128:256] (walk lists)
    {
        int blocksU = (N_USER + 15) / 16, blocksR = (N_REPO + 15) / 16;
        segsum_list<<<blocksU + blocksR, 256, 0, stream>>>(
            hRcat, head_ru, rec_ru, cnt_ru_s, hUcat, N_USER,
            hUcat, head_ur, rec_ur, cnt_ur_s, hRcat, N_REPO,
            256, 256, 128, 16, 16, blocksU);
    }
    // 4) hidden layer
    hidg<<<EGT, 256, 0, stream>>>(hUcat, hRcat, WTcat_u, WTcat_r,
                                  b_hcu, b_hru, b_hcr, b_hur, Fcat, Gcat);
    // 5) aggregate hidden into cat cols [96:192]
    {
        int blocksU = (N_USER + 20) / 21, blocksR = (N_REPO + 20) / 21;
        segsum_list<<<blocksU + blocksR, 256, 0, stream>>>(
            Gcat, head_ru, rec_ru, cnt_ru_s, Fcat, N_USER,
            Fcat, head_ur, rec_ur, cnt_ur_s, Gcat, N_REPO,
            192, 192, 96, 12, 21, blocksU);
    }
    // 6) output layer with fused in-register normalize
    outg<<<391 + 782, 256, 0, stream>>>(Fcat, Gcat, WTo_u, WTo_r,
                                        b_ocu, b_oru, b_ocr, b_our, hUn, hRn);
    // 7) scores
    score_all<<<(2L * NPAIR * 16 + 255) / 256, 256, 0, stream>>>(
        hUn, hRn, pos_u, pos_r, neg_u, neg_r, (float*)d_out);
}